// Round 1
// baseline (1038.554 us; speedup 1.0000x reference)
//
#include <hip/hip_runtime.h>
#include <math.h>

#define N_NODES 50000
#define E_EDGES 1600000

// ---------------- workspace layout (float units) ----------------
#define O_DEG   0
#define O_CNT   50048
#define O_DINV  100096
#define O_RPTR  150144
#define O_CUR   200192
#define O_COLS  250240
#define O_WNS   1850240
#define O_T1X   3450240
#define O_T2X   6650240
#define O_T1H   9850240
#define O_T2H   13050240
#define O_WP    16250240
// total ~16348544 floats = ~65.4 MB

__global__ void k_zero(float* __restrict__ p, int n) {
  int i = blockIdx.x * blockDim.x + threadIdx.x;
  if (i < n) p[i] = 0.f;
}

__global__ void k_edge_deg(const int* __restrict__ ei, const float* __restrict__ ew,
                           float* __restrict__ deg, int* __restrict__ cnt) {
  int i = blockIdx.x * blockDim.x + threadIdx.x;
  int stride = gridDim.x * blockDim.x;
  for (int e = i; e < E_EDGES; e += stride) {
    int r = ei[e], c = ei[E_EDGES + e];
    if (r != c) {
      atomicAdd(&deg[r], ew[e]);
      atomicAdd(&cnt[r], 1);
    }
  }
}

__global__ void k_dinv(const float* __restrict__ deg, float* __restrict__ dinv) {
  int i = blockIdx.x * blockDim.x + threadIdx.x;
  if (i < N_NODES) {
    float d = deg[i];
    dinv[i] = d > 0.f ? rsqrtf(d) : 0.f;
  }
}

// exclusive scan of cnt -> rptr and cursor (single block, 1024 threads)
__global__ void k_scan(const int* __restrict__ cnt, int* __restrict__ rptr,
                       int* __restrict__ cursor) {
  __shared__ int sh[1024];
  __shared__ int srun;
  int t = threadIdx.x;
  if (t == 0) srun = 0;
  __syncthreads();
  for (int base = 0; base < N_NODES; base += 1024) {
    int i = base + t;
    int v = (i < N_NODES) ? cnt[i] : 0;
    sh[t] = v;
    __syncthreads();
    for (int off = 1; off < 1024; off <<= 1) {
      int x = (t >= off) ? sh[t - off] : 0;
      __syncthreads();
      sh[t] += x;
      __syncthreads();
    }
    int incl = sh[t];
    int excl = incl - v;
    int run = srun;
    if (i < N_NODES) { rptr[i] = run + excl; cursor[i] = run + excl; }
    __syncthreads();
    if (t == 1023) srun = run + incl;
    __syncthreads();
  }
}

__global__ void k_edge_scatter(const int* __restrict__ ei, const float* __restrict__ ew,
                               const float* __restrict__ dinv, int* __restrict__ cursor,
                               int* __restrict__ col_s, float* __restrict__ wn_s) {
  int i = blockIdx.x * blockDim.x + threadIdx.x;
  int stride = gridDim.x * blockDim.x;
  for (int e = i; e < E_EDGES; e += stride) {
    int r = ei[e], c = ei[E_EDGES + e];
    if (r != c) {
      float w = -ew[e] * dinv[r] * dinv[c];
      int pos = atomicAdd(&cursor[r], 1);
      col_s[pos] = c;
      wn_s[pos] = w;
    }
  }
}

// out[row] = alpha*(L@src)[row] + beta*other[row]; one wave per row, lane = channel
__global__ __launch_bounds__(256) void k_spmm(
    const float* __restrict__ src, const float* __restrict__ other,
    float alpha, float beta,
    const int* __restrict__ rptr, const int* __restrict__ cnt,
    const int* __restrict__ col_s, const float* __restrict__ wn_s,
    float* __restrict__ out) {
  int wave = threadIdx.x >> 6;
  int lane = threadIdx.x & 63;
  int row = blockIdx.x * 4 + wave;
  if (row >= N_NODES) return;
  int start = rptr[row];
  int n = cnt[row];
  float acc = 0.f;
  for (int base = 0; base < n; base += 64) {
    int rem = n - base;
    int m = rem < 64 ? rem : 64;
    int ec = 0; float ev = 0.f;
    if (lane < m) {
      ec = col_s[start + base + lane];
      ev = wn_s[start + base + lane];
    }
    for (int j = 0; j < m; ++j) {
      int cc = __shfl(ec, j);
      float ww = __shfl(ev, j);
      acc = fmaf(ww, src[cc * 64 + lane], acc);
    }
  }
  float o = alpha * acc;
  if (beta != 0.f) o += beta * other[row * 64 + lane];
  out[row * 64 + lane] = o;
}

// pack weights: Wp[s][i][g*64+o], s in 0..5 = {X k0,k1,k2, H k0,k1,k2}, g = {i,f,c,o}
__global__ void k_pack(const float* __restrict__ Wxi, const float* __restrict__ Wxf,
                       const float* __restrict__ Wxc, const float* __restrict__ Wxo,
                       const float* __restrict__ Whi, const float* __restrict__ Whf,
                       const float* __restrict__ Whc, const float* __restrict__ Who,
                       float* __restrict__ Wp) {
  int idx = blockIdx.x * blockDim.x + threadIdx.x;
  if (idx >= 6 * 64 * 256) return;
  int s = idx >> 14;
  int i = (idx >> 8) & 63;
  int g = (idx >> 6) & 3;
  int o = idx & 63;
  const float* Wx[4] = {Wxi, Wxf, Wxc, Wxo};
  const float* Wh[4] = {Whi, Whf, Whc, Who};
  int ord = (s < 3) ? s : s - 3;
  const float* W = (s < 3) ? Wx[g] : Wh[g];
  Wp[idx] = W[(ord * 64 + i) * 64 + o];
}

// fused GEMM (Z[N,384] @ Wp[384,256]) + full LSTM pointwise epilogue
#define BM 32
__global__ __launch_bounds__(256) void k_gemm_lstm(
    const float* __restrict__ X, const float* __restrict__ T1X, const float* __restrict__ T2X,
    const float* __restrict__ H, const float* __restrict__ T1H, const float* __restrict__ T2H,
    const float* __restrict__ C, const float* __restrict__ Wp,
    const float* __restrict__ bxi, const float* __restrict__ bxf,
    const float* __restrict__ bxc, const float* __restrict__ bxo,
    const float* __restrict__ bhi, const float* __restrict__ bhf,
    const float* __restrict__ bhc, const float* __restrict__ bho,
    const float* __restrict__ wci, const float* __restrict__ wcf, const float* __restrict__ wco,
    const float* __restrict__ bi, const float* __restrict__ bf_,
    const float* __restrict__ bc_, const float* __restrict__ bo,
    float* __restrict__ Hout, float* __restrict__ Cout) {
  __shared__ float zs[BM][64];
  int tid = threadIdx.x;
  int lane = tid & 63;
  int rgrp = tid >> 6;  // 0..3
  int n0 = blockIdx.x * BM;
  float acc[8][4] = {};  // node = n0 + rgrp + 4*j
  const float* srcs[6] = {X, T1X, T2X, H, T1H, T2H};
  for (int s = 0; s < 6; ++s) {
    const float* S = srcs[s];
    __syncthreads();
    for (int t = tid; t < BM * 64; t += 256) {
      int r = t >> 6, cc = t & 63;
      int nn = n0 + r;
      zs[r][cc] = (nn < N_NODES) ? S[nn * 64 + cc] : 0.f;
    }
    __syncthreads();
    const float* Wbase = Wp + s * 64 * 256;
    for (int i = 0; i < 64; ++i) {
      float w0 = Wbase[i * 256 + 0 * 64 + lane];
      float w1 = Wbase[i * 256 + 1 * 64 + lane];
      float w2 = Wbase[i * 256 + 2 * 64 + lane];
      float w3 = Wbase[i * 256 + 3 * 64 + lane];
#pragma unroll
      for (int j = 0; j < 8; ++j) {
        float zv = zs[rgrp + 4 * j][i];
        acc[j][0] = fmaf(zv, w0, acc[j][0]);
        acc[j][1] = fmaf(zv, w1, acc[j][1]);
        acc[j][2] = fmaf(zv, w2, acc[j][2]);
        acc[j][3] = fmaf(zv, w3, acc[j][3]);
      }
    }
  }
  float bI = bxi[lane] + bhi[lane] + bi[lane];
  float bF = bxf[lane] + bhf[lane] + bf_[lane];
  float bT = bxc[lane] + bhc[lane] + bc_[lane];
  float bO = bxo[lane] + bho[lane] + bo[lane];
  float wcI = wci[lane], wcF = wcf[lane], wcO = wco[lane];
#pragma unroll
  for (int j = 0; j < 8; ++j) {
    int nn = n0 + rgrp + 4 * j;
    if (nn >= N_NODES) continue;
    float cv = C[nn * 64 + lane];
    float I = 1.f / (1.f + __expf(-(acc[j][0] + bI + wcI * cv)));
    float F = 1.f / (1.f + __expf(-(acc[j][1] + bF + wcF * cv)));
    float T = tanhf(acc[j][2] + bT);
    float cn = F * cv + I * T;
    float O = 1.f / (1.f + __expf(-(acc[j][3] + bO + wcO * cn)));
    float hn = O * tanhf(cn);
    Hout[nn * 64 + lane] = hn;
    Cout[nn * 64 + lane] = cn;
  }
}

extern "C" void kernel_launch(void* const* d_in, const int* in_sizes, int n_in,
                              void* d_out, int out_size, void* d_ws, size_t ws_size,
                              hipStream_t stream) {
  (void)in_sizes; (void)n_in; (void)out_size; (void)ws_size;
  const float* X   = (const float*)d_in[0];
  const int*   ei  = (const int*)d_in[1];
  const float* ew  = (const float*)d_in[2];
  const float* H   = (const float*)d_in[3];
  const float* C   = (const float*)d_in[4];
  const float* Wxi = (const float*)d_in[5];
  const float* bxi = (const float*)d_in[6];
  const float* Wxf = (const float*)d_in[7];
  const float* bxf = (const float*)d_in[8];
  const float* Wxc = (const float*)d_in[9];
  const float* bxc = (const float*)d_in[10];
  const float* Wxo = (const float*)d_in[11];
  const float* bxo = (const float*)d_in[12];
  const float* Whi = (const float*)d_in[13];
  const float* bhi = (const float*)d_in[14];
  const float* Whf = (const float*)d_in[15];
  const float* bhf = (const float*)d_in[16];
  const float* Whc = (const float*)d_in[17];
  const float* bhc = (const float*)d_in[18];
  const float* Who = (const float*)d_in[19];
  const float* bho = (const float*)d_in[20];
  const float* wci = (const float*)d_in[21];
  const float* wcf = (const float*)d_in[22];
  const float* wco = (const float*)d_in[23];
  const float* bi  = (const float*)d_in[24];
  const float* bf_ = (const float*)d_in[25];
  const float* bc_ = (const float*)d_in[26];
  const float* bo  = (const float*)d_in[27];

  float* ws = (float*)d_ws;
  float* deg    = ws + O_DEG;
  int*   cnt    = (int*)(ws + O_CNT);
  float* dinv   = ws + O_DINV;
  int*   rptr   = (int*)(ws + O_RPTR);
  int*   cursor = (int*)(ws + O_CUR);
  int*   col_s  = (int*)(ws + O_COLS);
  float* wn_s   = ws + O_WNS;
  float* T1X    = ws + O_T1X;
  float* T2X    = ws + O_T2X;
  float* T1H    = ws + O_T1H;
  float* T2H    = ws + O_T2H;
  float* Wp     = ws + O_WP;

  float* Hout = (float*)d_out;
  float* Cout = Hout + N_NODES * 64;

  // zero deg + cnt (contiguous: floats O_DEG .. O_DINV)
  k_zero<<<(O_DINV + 255) / 256, 256, 0, stream>>>(ws, O_DINV);
  k_edge_deg<<<1024, 256, 0, stream>>>(ei, ew, deg, cnt);
  k_dinv<<<(N_NODES + 255) / 256, 256, 0, stream>>>(deg, dinv);
  k_scan<<<1, 1024, 0, stream>>>(cnt, rptr, cursor);
  k_edge_scatter<<<1024, 256, 0, stream>>>(ei, ew, dinv, cursor, col_s, wn_s);
  k_pack<<<(6 * 64 * 256 + 255) / 256, 256, 0, stream>>>(Wxi, Wxf, Wxc, Wxo,
                                                         Whi, Whf, Whc, Who, Wp);
  int spmm_grid = (N_NODES + 3) / 4;
  k_spmm<<<spmm_grid, 256, 0, stream>>>(X, X, 1.f, 0.f, rptr, cnt, col_s, wn_s, T1X);
  k_spmm<<<spmm_grid, 256, 0, stream>>>(H, H, 1.f, 0.f, rptr, cnt, col_s, wn_s, T1H);
  k_spmm<<<spmm_grid, 256, 0, stream>>>(T1X, X, 2.f, -1.f, rptr, cnt, col_s, wn_s, T2X);
  k_spmm<<<spmm_grid, 256, 0, stream>>>(T1H, H, 2.f, -1.f, rptr, cnt, col_s, wn_s, T2H);
  k_gemm_lstm<<<(N_NODES + BM - 1) / BM, 256, 0, stream>>>(
      X, T1X, T2X, H, T1H, T2H, C, Wp,
      bxi, bxf, bxc, bxo, bhi, bhf, bhc, bho,
      wci, wcf, wco, bi, bf_, bc_, bo, Hout, Cout);
}

// Round 2
// 706.896 us; speedup vs baseline: 1.4692x; 1.4692x over previous
//
#include <hip/hip_runtime.h>
#include <math.h>

#define N_NODES 50000
#define E_EDGES 1600000

// ---------------- workspace layout (float units) ----------------
#define O_DEG   0
#define O_CNT   50048
#define O_DINV  100096
#define O_RPTR  150144
#define O_CUR   200192
#define O_COLS  250240
#define O_WNS   1850240
#define O_XH    3450240
#define O_T1    9850240
#define O_WP    16250240
// total 16348544 floats = ~65.4 MB

__global__ void k_zero(float* __restrict__ p, int n) {
  int i = blockIdx.x * blockDim.x + threadIdx.x;
  if (i < n) p[i] = 0.f;
}

__global__ void k_edge_deg(const int* __restrict__ ei, const float* __restrict__ ew,
                           float* __restrict__ deg, int* __restrict__ cnt) {
  int i = blockIdx.x * blockDim.x + threadIdx.x;
  int stride = gridDim.x * blockDim.x;
  for (int e = i; e < E_EDGES; e += stride) {
    int r = ei[e], c = ei[E_EDGES + e];
    if (r != c) {
      atomicAdd(&deg[r], ew[e]);
      atomicAdd(&cnt[r], 1);
    }
  }
}

__global__ void k_dinv(const float* __restrict__ deg, float* __restrict__ dinv) {
  int i = blockIdx.x * blockDim.x + threadIdx.x;
  if (i < N_NODES) {
    float d = deg[i];
    dinv[i] = d > 0.f ? rsqrtf(d) : 0.f;
  }
}

// exclusive scan of cnt -> rptr and cursor; single block, 1024 threads, shfl-based
__global__ __launch_bounds__(1024) void k_scan(const int* __restrict__ cnt,
                                               int* __restrict__ rptr,
                                               int* __restrict__ cursor) {
  __shared__ int wsum[16];
  __shared__ int srun;
  int t = threadIdx.x;
  int lane = t & 63, wid = t >> 6;  // 16 waves
  if (t == 0) srun = 0;
  __syncthreads();
  for (int base = 0; base < N_NODES; base += 1024) {
    int i = base + t;
    int v = (i < N_NODES) ? cnt[i] : 0;
    int x = v;  // inclusive wave scan
#pragma unroll
    for (int off = 1; off < 64; off <<= 1) {
      int y = __shfl_up(x, off);
      if (lane >= off) x += y;
    }
    if (lane == 63) wsum[wid] = x;
    __syncthreads();
    if (wid == 0) {
      int s = (lane < 16) ? wsum[lane] : 0;
#pragma unroll
      for (int off = 1; off < 16; off <<= 1) {
        int y = __shfl_up(s, off);
        if (lane >= off) s += y;
      }
      if (lane < 16) wsum[lane] = s;  // inclusive wave sums
    }
    __syncthreads();
    int woff = (wid > 0) ? wsum[wid - 1] : 0;
    int incl = x + woff;
    int run = srun;
    __syncthreads();  // everyone has read srun
    int excl = incl - v;
    if (i < N_NODES) { rptr[i] = run + excl; cursor[i] = run + excl; }
    if (t == 1023) srun = run + incl;
    __syncthreads();  // srun update + wsum reads done before next iter
  }
}

__global__ void k_edge_scatter(const int* __restrict__ ei, const float* __restrict__ ew,
                               const float* __restrict__ dinv, int* __restrict__ cursor,
                               int* __restrict__ col_s, float* __restrict__ wn_s) {
  int i = blockIdx.x * blockDim.x + threadIdx.x;
  int stride = gridDim.x * blockDim.x;
  for (int e = i; e < E_EDGES; e += stride) {
    int r = ei[e], c = ei[E_EDGES + e];
    if (r != c) {
      float w = -ew[e] * dinv[r] * dinv[c];
      int pos = atomicAdd(&cursor[r], 1);
      col_s[pos] = c;
      wn_s[pos] = w;
    }
  }
}

// XH[n][0..63] = X[n], XH[n][64..127] = H[n]  (float4 granularity)
__global__ void k_xh(const float* __restrict__ X, const float* __restrict__ Hm,
                     float* __restrict__ XH) {
  int t = blockIdx.x * blockDim.x + threadIdx.x;
  if (t >= N_NODES * 32) return;
  int n = t >> 5, q = t & 31;
  float4 v = (q < 16) ? ((const float4*)X)[n * 16 + q]
                      : ((const float4*)Hm)[n * 16 + (q - 16)];
  ((float4*)XH)[t] = v;
}

// out[row][0..127] = alpha*(L@src)[row] + beta*other[row]; wave/row, lane = 2 channels
__global__ __launch_bounds__(256) void k_spmm2(
    const float* __restrict__ src, const float* __restrict__ other,
    float alpha, float beta,
    const int* __restrict__ rptr, const int* __restrict__ cnt,
    const int* __restrict__ col_s, const float* __restrict__ wn_s,
    float* __restrict__ out) {
  int wid = threadIdx.x >> 6, lane = threadIdx.x & 63;
  int row = blockIdx.x * 4 + wid;
  if (row >= N_NODES) return;
  int start = rptr[row], n = cnt[row];
  float ax = 0.f, ay = 0.f;
  for (int base = 0; base < n; base += 64) {
    int rem = n - base;
    int m = rem < 64 ? rem : 64;
    int ec = 0; float ev = 0.f;
    if (lane < m) {
      ec = col_s[start + base + lane];
      ev = wn_s[start + base + lane];
    }
    int j = 0;
    for (; j + 4 <= m; j += 4) {
#pragma unroll
      for (int u = 0; u < 4; ++u) {
        int cc = __shfl(ec, j + u);
        float ww = __shfl(ev, j + u);
        float2 v = *(const float2*)(src + (long)cc * 128 + lane * 2);
        ax = fmaf(ww, v.x, ax);
        ay = fmaf(ww, v.y, ay);
      }
    }
    for (; j < m; ++j) {
      int cc = __shfl(ec, j);
      float ww = __shfl(ev, j);
      float2 v = *(const float2*)(src + (long)cc * 128 + lane * 2);
      ax = fmaf(ww, v.x, ax);
      ay = fmaf(ww, v.y, ay);
    }
  }
  float ox = alpha * ax, oy = alpha * ay;
  if (beta != 0.f) {
    float2 ov = *(const float2*)(other + (long)row * 128 + lane * 2);
    ox += beta * ov.x;
    oy += beta * ov.y;
  }
  float2 o; o.x = ox; o.y = oy;
  *(float2*)(out + (long)row * 128 + lane * 2) = o;
}

// weight pack: Wp[s][k][o][g], s = {Xk0,Hk0,Xk1,Hk1,Xk2,Hk2}, g = {i,f,c,o}
__global__ void k_pack(const float* __restrict__ Wxi, const float* __restrict__ Wxf,
                       const float* __restrict__ Wxc, const float* __restrict__ Wxo,
                       const float* __restrict__ Whi, const float* __restrict__ Whf,
                       const float* __restrict__ Whc, const float* __restrict__ Who,
                       float* __restrict__ Wp) {
  int idx = blockIdx.x * blockDim.x + threadIdx.x;
  if (idx >= 6 * 64 * 64 * 4) return;
  int g = idx & 3;
  int o = (idx >> 2) & 63;
  int k = (idx >> 8) & 63;
  int s = idx >> 14;
  const float* Wx[4] = {Wxi, Wxf, Wxc, Wxo};
  const float* Wh[4] = {Whi, Whf, Whc, Who};
  int ord = s >> 1;
  const float* W = (s & 1) ? Wh[g] : Wx[g];
  Wp[idx] = W[(ord * 64 + k) * 64 + o];
}

// fused GEMM (Z[N,384] @ W[384,256]) + LSTM pointwise epilogue
#define BM 32
__global__ __launch_bounds__(256) void k_gemm_lstm(
    const float* __restrict__ X, const float* __restrict__ Hm,
    const float* __restrict__ T1, const float* __restrict__ T2,
    const float* __restrict__ C, const float* __restrict__ Wp,
    const float* __restrict__ bxi, const float* __restrict__ bxf,
    const float* __restrict__ bxc, const float* __restrict__ bxo,
    const float* __restrict__ bhi, const float* __restrict__ bhf,
    const float* __restrict__ bhc, const float* __restrict__ bho,
    const float* __restrict__ wci, const float* __restrict__ wcf, const float* __restrict__ wco,
    const float* __restrict__ bi, const float* __restrict__ bf_,
    const float* __restrict__ bc_, const float* __restrict__ bo,
    float* __restrict__ Hout, float* __restrict__ Cout) {
  __shared__ float zs[BM][65];
  int tid = threadIdx.x;
  int lane = tid & 63;
  int wid = tid >> 6;  // 0..3, wave handles rows wid*8..wid*8+7
  int n0 = blockIdx.x * BM;
  float acc[8][4] = {};
  const float* bases[6] = {X, Hm, T1, T1 + 64, T2, T2 + 64};
  const int strides[6] = {64, 64, 128, 128, 128, 128};
  for (int s = 0; s < 6; ++s) {
    const float* B = bases[s];
    int st = strides[s];
    __syncthreads();
    for (int t = tid; t < BM * 64; t += 256) {
      int r = t >> 6, cc = t & 63;
      int nn = n0 + r;
      zs[r][cc] = (nn < N_NODES) ? B[(long)nn * st + cc] : 0.f;
    }
    __syncthreads();
    const float* Wb = Wp + s * (64 * 256);
#pragma unroll 4
    for (int i = 0; i < 64; ++i) {
      float4 w = *(const float4*)(Wb + (i * 64 + lane) * 4);
#pragma unroll
      for (int j = 0; j < 8; ++j) {
        float zv = zs[wid * 8 + j][i];
        acc[j][0] = fmaf(zv, w.x, acc[j][0]);
        acc[j][1] = fmaf(zv, w.y, acc[j][1]);
        acc[j][2] = fmaf(zv, w.z, acc[j][2]);
        acc[j][3] = fmaf(zv, w.w, acc[j][3]);
      }
    }
  }
  float bI = bxi[lane] + bhi[lane] + bi[lane];
  float bF = bxf[lane] + bhf[lane] + bf_[lane];
  float bT = bxc[lane] + bhc[lane] + bc_[lane];
  float bO = bxo[lane] + bho[lane] + bo[lane];
  float wcI = wci[lane], wcF = wcf[lane], wcO = wco[lane];
#pragma unroll
  for (int j = 0; j < 8; ++j) {
    int nn = n0 + wid * 8 + j;
    if (nn >= N_NODES) continue;
    float cv = C[(long)nn * 64 + lane];
    float I = 1.f / (1.f + __expf(-(acc[j][0] + bI + wcI * cv)));
    float F = 1.f / (1.f + __expf(-(acc[j][1] + bF + wcF * cv)));
    float T = tanhf(acc[j][2] + bT);
    float cn = F * cv + I * T;
    float O = 1.f / (1.f + __expf(-(acc[j][3] + bO + wcO * cn)));
    float hn = O * tanhf(cn);
    Hout[(long)nn * 64 + lane] = hn;
    Cout[(long)nn * 64 + lane] = cn;
  }
}

extern "C" void kernel_launch(void* const* d_in, const int* in_sizes, int n_in,
                              void* d_out, int out_size, void* d_ws, size_t ws_size,
                              hipStream_t stream) {
  (void)in_sizes; (void)n_in; (void)out_size; (void)ws_size;
  const float* X   = (const float*)d_in[0];
  const int*   ei  = (const int*)d_in[1];
  const float* ew  = (const float*)d_in[2];
  const float* H   = (const float*)d_in[3];
  const float* C   = (const float*)d_in[4];
  const float* Wxi = (const float*)d_in[5];
  const float* bxi = (const float*)d_in[6];
  const float* Wxf = (const float*)d_in[7];
  const float* bxf = (const float*)d_in[8];
  const float* Wxc = (const float*)d_in[9];
  const float* bxc = (const float*)d_in[10];
  const float* Wxo = (const float*)d_in[11];
  const float* bxo = (const float*)d_in[12];
  const float* Whi = (const float*)d_in[13];
  const float* bhi = (const float*)d_in[14];
  const float* Whf = (const float*)d_in[15];
  const float* bhf = (const float*)d_in[16];
  const float* Whc = (const float*)d_in[17];
  const float* bhc = (const float*)d_in[18];
  const float* Who = (const float*)d_in[19];
  const float* bho = (const float*)d_in[20];
  const float* wci = (const float*)d_in[21];
  const float* wcf = (const float*)d_in[22];
  const float* wco = (const float*)d_in[23];
  const float* bi  = (const float*)d_in[24];
  const float* bf_ = (const float*)d_in[25];
  const float* bc_ = (const float*)d_in[26];
  const float* bo  = (const float*)d_in[27];

  float* ws = (float*)d_ws;
  float* deg    = ws + O_DEG;
  int*   cnt    = (int*)(ws + O_CNT);
  float* dinv   = ws + O_DINV;
  int*   rptr   = (int*)(ws + O_RPTR);
  int*   cursor = (int*)(ws + O_CUR);
  int*   col_s  = (int*)(ws + O_COLS);
  float* wn_s   = ws + O_WNS;
  float* XH     = ws + O_XH;   // becomes T2 in-place after pass 2
  float* T1     = ws + O_T1;
  float* Wp     = ws + O_WP;

  float* Hout = (float*)d_out;
  float* Cout = Hout + N_NODES * 64;

  k_zero<<<(O_DINV + 255) / 256, 256, 0, stream>>>(ws, O_DINV);
  k_edge_deg<<<1024, 256, 0, stream>>>(ei, ew, deg, cnt);
  k_dinv<<<(N_NODES + 255) / 256, 256, 0, stream>>>(deg, dinv);
  k_scan<<<1, 1024, 0, stream>>>(cnt, rptr, cursor);
  k_edge_scatter<<<1024, 256, 0, stream>>>(ei, ew, dinv, cursor, col_s, wn_s);
  k_xh<<<(N_NODES * 32 + 255) / 256, 256, 0, stream>>>(X, H, XH);
  k_pack<<<(6 * 64 * 64 * 4 + 255) / 256, 256, 0, stream>>>(Wxi, Wxf, Wxc, Wxo,
                                                            Whi, Whf, Whc, Who, Wp);
  int spmm_grid = (N_NODES + 3) / 4;
  // T1 = L @ XH
  k_spmm2<<<spmm_grid, 256, 0, stream>>>(XH, XH, 1.f, 0.f, rptr, cnt, col_s, wn_s, T1);
  // T2 = 2 L @ T1 - XH   (in-place over XH: gathers read T1 only)
  k_spmm2<<<spmm_grid, 256, 0, stream>>>(T1, XH, 2.f, -1.f, rptr, cnt, col_s, wn_s, XH);
  k_gemm_lstm<<<(N_NODES + BM - 1) / BM, 256, 0, stream>>>(
      X, H, T1, XH, C, Wp,
      bxi, bxf, bxc, bxo, bhi, bhf, bhc, bho,
      wci, wcf, wco, bi, bf_, bc_, bo, Hout, Cout);
}

// Round 3
// 472.332 us; speedup vs baseline: 2.1988x; 1.4966x over previous
//
#include <hip/hip_runtime.h>
#include <hip/hip_bf16.h>
#include <math.h>

#define N_NODES 50000
#define E_EDGES 1600000

typedef __attribute__((ext_vector_type(8))) short s8v;    // 8 bf16 frag
typedef __attribute__((ext_vector_type(4))) float f32x4;  // mfma acc

// ---------------- workspace layout (float units) ----------------
#define O_DEG   0
#define O_CNT   50048
#define O_DINV  100096
#define O_RPTR  150144
#define O_CUR   200192
#define O_EDGE  250240            // 1.6M packed u32 (col<<16 | bf16(wn))
#define O_XHB   1850240           // 50048*128 bf16 = 3203072 floats
#define O_T1B   5053312
#define O_T2B   8256384
#define O_BP    11459456          // 98304 bf16 = 49152 floats
// end: 11508608 floats ~= 46 MB

__device__ __forceinline__ uint pk_bf16(float x, float y) {
  __hip_bfloat16 bx = __float2bfloat16(x), by = __float2bfloat16(y);
  ushort ux = *reinterpret_cast<ushort*>(&bx);
  ushort uy = *reinterpret_cast<ushort*>(&by);
  return ((uint)uy << 16) | (uint)ux;
}

__global__ void k_zero(float* __restrict__ p, int n) {
  int i = blockIdx.x * blockDim.x + threadIdx.x;
  if (i < n) p[i] = 0.f;
}

__global__ void k_edge_deg(const int* __restrict__ ei, const float* __restrict__ ew,
                           float* __restrict__ deg, int* __restrict__ cnt) {
  int i = blockIdx.x * blockDim.x + threadIdx.x;
  int stride = gridDim.x * blockDim.x;
  for (int e = i; e < E_EDGES; e += stride) {
    int r = ei[e], c = ei[E_EDGES + e];
    if (r != c) {
      atomicAdd(&deg[r], ew[e]);
      atomicAdd(&cnt[r], 1);
    }
  }
}

__global__ void k_dinv(const float* __restrict__ deg, float* __restrict__ dinv) {
  int i = blockIdx.x * blockDim.x + threadIdx.x;
  if (i < N_NODES) {
    float d = deg[i];
    dinv[i] = d > 0.f ? rsqrtf(d) : 0.f;
  }
}

// exclusive scan of cnt -> rptr and cursor; single block, 1024 threads, shfl-based
__global__ __launch_bounds__(1024) void k_scan(const int* __restrict__ cnt,
                                               int* __restrict__ rptr,
                                               int* __restrict__ cursor) {
  __shared__ int wsum[16];
  __shared__ int srun;
  int t = threadIdx.x;
  int lane = t & 63, wid = t >> 6;
  if (t == 0) srun = 0;
  __syncthreads();
  for (int base = 0; base < N_NODES; base += 1024) {
    int i = base + t;
    int v = (i < N_NODES) ? cnt[i] : 0;
    int x = v;
#pragma unroll
    for (int off = 1; off < 64; off <<= 1) {
      int y = __shfl_up(x, off);
      if (lane >= off) x += y;
    }
    if (lane == 63) wsum[wid] = x;
    __syncthreads();
    if (wid == 0) {
      int s = (lane < 16) ? wsum[lane] : 0;
#pragma unroll
      for (int off = 1; off < 16; off <<= 1) {
        int y = __shfl_up(s, off);
        if (lane >= off) s += y;
      }
      if (lane < 16) wsum[lane] = s;
    }
    __syncthreads();
    int woff = (wid > 0) ? wsum[wid - 1] : 0;
    int incl = x + woff;
    int run = srun;
    __syncthreads();
    int excl = incl - v;
    if (i < N_NODES) { rptr[i] = run + excl; cursor[i] = run + excl; }
    if (t == 1023) srun = run + incl;
    __syncthreads();
  }
}

__global__ void k_edge_scatter(const int* __restrict__ ei, const float* __restrict__ ew,
                               const float* __restrict__ dinv, int* __restrict__ cursor,
                               uint* __restrict__ edges) {
  int i = blockIdx.x * blockDim.x + threadIdx.x;
  int stride = gridDim.x * blockDim.x;
  for (int e = i; e < E_EDGES; e += stride) {
    int r = ei[e], c = ei[E_EDGES + e];
    if (r != c) {
      float w = -ew[e] * dinv[r] * dinv[c];
      __hip_bfloat16 bw = __float2bfloat16(w);
      ushort uw = *reinterpret_cast<ushort*>(&bw);
      int pos = atomicAdd(&cursor[r], 1);
      edges[pos] = ((uint)c << 16) | (uint)uw;
    }
  }
}

// XHb[n] = bf16x2-packed [X[n] | H[n]]  (u32 = 2 channels per thread)
__global__ void k_xhb(const float* __restrict__ X, const float* __restrict__ Hm,
                      uint* __restrict__ XHb) {
  int t = blockIdx.x * blockDim.x + threadIdx.x;
  if (t >= N_NODES * 64) return;
  int n = t >> 6, q = t & 63;
  float2 v = (q < 32) ? *(const float2*)(X + (long)n * 64 + q * 2)
                      : *(const float2*)(Hm + (long)n * 64 + (q - 32) * 2);
  XHb[t] = pk_bf16(v.x, v.y);
}

// out[row] = alpha*(L@src)[row] + beta*other[row]; wave/row, lane = 2 bf16 channels
__global__ __launch_bounds__(256) void k_spmm2b(
    const uint* __restrict__ src, const uint* __restrict__ other,
    float alpha, float beta,
    const int* __restrict__ rptr, const int* __restrict__ cnt,
    const uint* __restrict__ edges, uint* __restrict__ out) {
  int wid = threadIdx.x >> 6, lane = threadIdx.x & 63;
  int row = blockIdx.x * 4 + wid;
  if (row >= N_NODES) return;
  int start = rptr[row], n = cnt[row];
  float ax = 0.f, ay = 0.f;
  for (int base = 0; base < n; base += 64) {
    int rem = n - base;
    int m = rem < 64 ? rem : 64;
    uint rec = (lane < m) ? edges[start + base + lane] : 0u;
    int j = 0;
    for (; j + 4 <= m; j += 4) {
#pragma unroll
      for (int u = 0; u < 4; ++u) {
        uint r = __shfl(rec, j + u);
        int cc = (int)(r >> 16);
        float ww = __uint_as_float(r << 16);
        uint z = src[cc * 64 + lane];
        ax = fmaf(ww, __uint_as_float(z << 16), ax);
        ay = fmaf(ww, __uint_as_float(z & 0xffff0000u), ay);
      }
    }
    for (; j < m; ++j) {
      uint r = __shfl(rec, j);
      int cc = (int)(r >> 16);
      float ww = __uint_as_float(r << 16);
      uint z = src[cc * 64 + lane];
      ax = fmaf(ww, __uint_as_float(z << 16), ax);
      ay = fmaf(ww, __uint_as_float(z & 0xffff0000u), ay);
    }
  }
  float ox = alpha * ax, oy = alpha * ay;
  if (beta != 0.f) {
    uint ov = other[row * 64 + lane];
    ox += beta * __uint_as_float(ov << 16);
    oy += beta * __uint_as_float(ov & 0xffff0000u);
  }
  out[row * 64 + lane] = pk_bf16(ox, oy);
}

// B-frag pack: Bp[((t*16+c)*64+lane)*8+j] = bf16(W[k][col]), k=t*32+(lane>>4)*8+j,
// col = c*16+(lane&15); col = g*64+oc; k-slice s=k/64: even->Wx[g], odd->Wh[g], ord=s>>1
__global__ void k_pack(const float* __restrict__ Wxi, const float* __restrict__ Wxf,
                       const float* __restrict__ Wxc, const float* __restrict__ Wxo,
                       const float* __restrict__ Whi, const float* __restrict__ Whf,
                       const float* __restrict__ Whc, const float* __restrict__ Who,
                       ushort* __restrict__ Bp) {
  int idx = blockIdx.x * blockDim.x + threadIdx.x;
  if (idx >= 12 * 16 * 64 * 8) return;
  int j = idx & 7;
  int lane = (idx >> 3) & 63;
  int c = (idx >> 9) & 15;
  int t = idx >> 13;
  int k = t * 32 + (lane >> 4) * 8 + j;
  int col = c * 16 + (lane & 15);
  int g = col >> 6, oc = col & 63;
  int s = k >> 6, kk = k & 63, ord = s >> 1;
  const float* Wx[4] = {Wxi, Wxf, Wxc, Wxo};
  const float* Wh[4] = {Whi, Whf, Whc, Who};
  const float* W = (s & 1) ? Wh[g] : Wx[g];
  float v = W[(ord * 64 + kk) * 64 + oc];
  __hip_bfloat16 b = __float2bfloat16(v);
  Bp[idx] = *reinterpret_cast<ushort*>(&b);
}

// MFMA GEMM: [XHb|T1b|T2b][N,384] @ W[384,256] + fused LSTM epilogue.
// Block = 4 waves x 16 rows = 64 rows; wave computes 16x256 via 16 16x16x32 tiles.
__global__ __launch_bounds__(256) void k_mfma_lstm(
    const ushort* __restrict__ XHb, const ushort* __restrict__ T1b,
    const ushort* __restrict__ T2b, const float* __restrict__ C,
    const ushort* __restrict__ Bp,
    const float* __restrict__ bxi, const float* __restrict__ bxf,
    const float* __restrict__ bxc, const float* __restrict__ bxo,
    const float* __restrict__ bhi, const float* __restrict__ bhf,
    const float* __restrict__ bhc, const float* __restrict__ bho,
    const float* __restrict__ wci, const float* __restrict__ wcf, const float* __restrict__ wco,
    const float* __restrict__ bi, const float* __restrict__ bf_,
    const float* __restrict__ bc_, const float* __restrict__ bo,
    float* __restrict__ Hout, float* __restrict__ Cout) {
  int lane = threadIdx.x & 63, wid = threadIdx.x >> 6;
  int row0 = blockIdx.x * 64 + wid * 16;
  int arow = row0 + (lane & 15);
  f32x4 acc[16];
#pragma unroll
  for (int c = 0; c < 16; ++c) acc[c] = {0.f, 0.f, 0.f, 0.f};
  const ushort* arrs[3] = {XHb, T1b, T2b};
  for (int t = 0; t < 12; ++t) {
    const ushort* A = arrs[t >> 2];
    int coff = (t & 3) * 32 + (lane >> 4) * 8;
    s8v a = *(const s8v*)(A + (long)arow * 128 + coff);
    const ushort* bp = Bp + (long)t * 8192 + lane * 8;
#pragma unroll
    for (int c = 0; c < 16; ++c) {
      s8v b = *(const s8v*)(bp + c * 512);
      acc[c] = __builtin_amdgcn_mfma_f32_16x16x32_bf16(a, b, acc[c], 0, 0, 0);
    }
  }
  // epilogue: C/D layout col=lane&15 (within tile), row=(lane>>4)*4+reg
  int rbase = row0 + ((lane >> 4) << 2);
  int ocl = lane & 15;
#pragma unroll
  for (int j = 0; j < 4; ++j) {
    int oc = j * 16 + ocl;
    float bI = bxi[oc] + bhi[oc] + bi[oc];
    float bF = bxf[oc] + bhf[oc] + bf_[oc];
    float bT = bxc[oc] + bhc[oc] + bc_[oc];
    float bO = bxo[oc] + bho[oc] + bo[oc];
    float wcI = wci[oc], wcF = wcf[oc], wcO = wco[oc];
#pragma unroll
    for (int r = 0; r < 4; ++r) {
      int row = rbase + r;
      if (row < N_NODES) {
        float cv = C[(long)row * 64 + oc];
        float I = 1.f / (1.f + __expf(-(acc[j][r] + bI + wcI * cv)));
        float F = 1.f / (1.f + __expf(-(acc[4 + j][r] + bF + wcF * cv)));
        float e2 = __expf(2.f * (acc[8 + j][r] + bT));
        float T = 1.f - 2.f / (e2 + 1.f);
        float cn = F * cv + I * T;
        float O = 1.f / (1.f + __expf(-(acc[12 + j][r] + bO + wcO * cn)));
        float e2c = __expf(2.f * cn);
        float tc = 1.f - 2.f / (e2c + 1.f);
        Hout[(long)row * 64 + oc] = O * tc;
        Cout[(long)row * 64 + oc] = cn;
      }
    }
  }
}

extern "C" void kernel_launch(void* const* d_in, const int* in_sizes, int n_in,
                              void* d_out, int out_size, void* d_ws, size_t ws_size,
                              hipStream_t stream) {
  (void)in_sizes; (void)n_in; (void)out_size; (void)ws_size;
  const float* X   = (const float*)d_in[0];
  const int*   ei  = (const int*)d_in[1];
  const float* ew  = (const float*)d_in[2];
  const float* H   = (const float*)d_in[3];
  const float* C   = (const float*)d_in[4];
  const float* Wxi = (const float*)d_in[5];
  const float* bxi = (const float*)d_in[6];
  const float* Wxf = (const float*)d_in[7];
  const float* bxf = (const float*)d_in[8];
  const float* Wxc = (const float*)d_in[9];
  const float* bxc = (const float*)d_in[10];
  const float* Wxo = (const float*)d_in[11];
  const float* bxo = (const float*)d_in[12];
  const float* Whi = (const float*)d_in[13];
  const float* bhi = (const float*)d_in[14];
  const float* Whf = (const float*)d_in[15];
  const float* bhf = (const float*)d_in[16];
  const float* Whc = (const float*)d_in[17];
  const float* bhc = (const float*)d_in[18];
  const float* Who = (const float*)d_in[19];
  const float* bho = (const float*)d_in[20];
  const float* wci = (const float*)d_in[21];
  const float* wcf = (const float*)d_in[22];
  const float* wco = (const float*)d_in[23];
  const float* bi  = (const float*)d_in[24];
  const float* bf_ = (const float*)d_in[25];
  const float* bc_ = (const float*)d_in[26];
  const float* bo  = (const float*)d_in[27];

  float* ws = (float*)d_ws;
  float*  deg    = ws + O_DEG;
  int*    cnt    = (int*)(ws + O_CNT);
  float*  dinv   = ws + O_DINV;
  int*    rptr   = (int*)(ws + O_RPTR);
  int*    cursor = (int*)(ws + O_CUR);
  uint*   edges  = (uint*)(ws + O_EDGE);
  uint*   XHb    = (uint*)(ws + O_XHB);
  uint*   T1b    = (uint*)(ws + O_T1B);
  uint*   T2b    = (uint*)(ws + O_T2B);
  ushort* Bp     = (ushort*)(ws + O_BP);

  float* Hout = (float*)d_out;
  float* Cout = Hout + N_NODES * 64;

  k_zero<<<(O_DINV + 255) / 256, 256, 0, stream>>>(ws, O_DINV);
  k_edge_deg<<<1024, 256, 0, stream>>>(ei, ew, deg, cnt);
  k_dinv<<<(N_NODES + 255) / 256, 256, 0, stream>>>(deg, dinv);
  k_scan<<<1, 1024, 0, stream>>>(cnt, rptr, cursor);
  k_edge_scatter<<<1024, 256, 0, stream>>>(ei, ew, dinv, cursor, edges);
  k_xhb<<<(N_NODES * 64 + 255) / 256, 256, 0, stream>>>(X, H, XHb);
  k_pack<<<(12 * 16 * 64 * 8 + 255) / 256, 256, 0, stream>>>(Wxi, Wxf, Wxc, Wxo,
                                                             Whi, Whf, Whc, Who, Bp);
  int spmm_grid = (N_NODES + 3) / 4;
  // T1 = L @ XH
  k_spmm2b<<<spmm_grid, 256, 0, stream>>>(XHb, XHb, 1.f, 0.f, rptr, cnt, edges, T1b);
  // T2 = 2 L @ T1 - XH
  k_spmm2b<<<spmm_grid, 256, 0, stream>>>(T1b, XHb, 2.f, -1.f, rptr, cnt, edges, T2b);
  k_mfma_lstm<<<(N_NODES + 63) / 64, 256, 0, stream>>>(
      (const ushort*)XHb, (const ushort*)T1b, (const ushort*)T2b, C, Bp,
      bxi, bxf, bxc, bxo, bhi, bhf, bhc, bho,
      wci, wcf, wco, bi, bf_, bc_, bo, Hout, Cout);
}

// Round 4
// 344.199 us; speedup vs baseline: 3.0173x; 1.3723x over previous
//
#include <hip/hip_runtime.h>
#include <hip/hip_bf16.h>
#include <math.h>

#define N_NODES 50000
#define E_EDGES 1600000

typedef __attribute__((ext_vector_type(8))) short s8v;    // 8 bf16 frag
typedef __attribute__((ext_vector_type(4))) float f32x4;  // mfma acc

// ---------------- workspace layout (float units) ----------------
#define O_DC    0                 // 50000 u64 (cnt<<40 | fixed24 wsum)
#define O_CNT   100096
#define O_DINV  150144
#define O_RPTR  200192
#define O_RANK  250240            // 1.6M u16 rank-within-row
#define O_EDGE  1050240           // 1.6M packed u32 (col<<16 | bf16(wn))
#define O_XHB   2650240           // 50000*128 bf16 = 3200000 floats
#define O_T1B   5850240
#define O_T2B   9050240
#define O_BP    12250240          // 98304 bf16 = 49152 floats
// end: 12299392 floats ~= 49.2 MB

__device__ __forceinline__ uint pk_bf16(float x, float y) {
  __hip_bfloat16 bx = __float2bfloat16(x), by = __float2bfloat16(y);
  ushort ux = *reinterpret_cast<ushort*>(&bx);
  ushort uy = *reinterpret_cast<ushort*>(&by);
  return ((uint)uy << 16) | (uint)ux;
}

__global__ void k_zero(float* __restrict__ p, int n) {
  int i = blockIdx.x * blockDim.x + threadIdx.x;
  if (i < n) p[i] = 0.f;
}

// one u64 atomic per edge: high24 = count, low40 = sum(w * 2^24).
// returned old value's count field = this edge's rank within its row.
__global__ void k_edge_deg(const int* __restrict__ ei, const float* __restrict__ ew,
                           unsigned long long* __restrict__ dc,
                           ushort* __restrict__ rank) {
  int i = blockIdx.x * blockDim.x + threadIdx.x;
  int stride = gridDim.x * blockDim.x;
  for (int e = i; e < E_EDGES; e += stride) {
    int r = ei[e], c = ei[E_EDGES + e];
    ushort rk = 0;
    if (r != c) {
      unsigned long long pack =
          (1ull << 40) | (unsigned long long)(ew[e] * 16777216.0f + 0.5f);
      unsigned long long old = atomicAdd(&dc[r], pack);
      rk = (ushort)(old >> 40);
    }
    rank[e] = rk;
  }
}

__global__ void k_dinv(const unsigned long long* __restrict__ dc,
                       int* __restrict__ cnt, float* __restrict__ dinv) {
  int i = blockIdx.x * blockDim.x + threadIdx.x;
  if (i < N_NODES) {
    unsigned long long v = dc[i];
    int c = (int)(v >> 40);
    float d = (float)(v & 0xFFFFFFFFFFull) * (1.0f / 16777216.0f);
    cnt[i] = c;
    dinv[i] = d > 0.f ? rsqrtf(d) : 0.f;
  }
}

// exclusive scan of cnt -> rptr; single block, 1024 threads, shfl-based
__global__ __launch_bounds__(1024) void k_scan(const int* __restrict__ cnt,
                                               int* __restrict__ rptr) {
  __shared__ int wsum[16];
  __shared__ int srun;
  int t = threadIdx.x;
  int lane = t & 63, wid = t >> 6;
  if (t == 0) srun = 0;
  __syncthreads();
  for (int base = 0; base < N_NODES; base += 1024) {
    int i = base + t;
    int v = (i < N_NODES) ? cnt[i] : 0;
    int x = v;
#pragma unroll
    for (int off = 1; off < 64; off <<= 1) {
      int y = __shfl_up(x, off);
      if (lane >= off) x += y;
    }
    if (lane == 63) wsum[wid] = x;
    __syncthreads();
    if (wid == 0) {
      int s = (lane < 16) ? wsum[lane] : 0;
#pragma unroll
      for (int off = 1; off < 16; off <<= 1) {
        int y = __shfl_up(s, off);
        if (lane >= off) s += y;
      }
      if (lane < 16) wsum[lane] = s;
    }
    __syncthreads();
    int woff = (wid > 0) ? wsum[wid - 1] : 0;
    int incl = x + woff;
    int run = srun;
    __syncthreads();
    int excl = incl - v;
    if (i < N_NODES) rptr[i] = run + excl;
    if (t == 1023) srun = run + incl;
    __syncthreads();
  }
}

// atomic-free scatter: pos = rptr[row] + rank[e]
__global__ void k_edge_scatter(const int* __restrict__ ei, const float* __restrict__ ew,
                               const float* __restrict__ dinv,
                               const int* __restrict__ rptr,
                               const ushort* __restrict__ rank,
                               uint* __restrict__ edges) {
  int i = blockIdx.x * blockDim.x + threadIdx.x;
  int stride = gridDim.x * blockDim.x;
  for (int e = i; e < E_EDGES; e += stride) {
    int r = ei[e], c = ei[E_EDGES + e];
    if (r != c) {
      float w = -ew[e] * dinv[r] * dinv[c];
      __hip_bfloat16 bw = __float2bfloat16(w);
      ushort uw = *reinterpret_cast<ushort*>(&bw);
      int pos = rptr[r] + (int)rank[e];
      edges[pos] = ((uint)c << 16) | (uint)uw;
    }
  }
}

// XHb[n] = bf16x2-packed [X[n] | H[n]]  (u32 = 2 channels per thread)
__global__ void k_xhb(const float* __restrict__ X, const float* __restrict__ Hm,
                      uint* __restrict__ XHb) {
  int t = blockIdx.x * blockDim.x + threadIdx.x;
  if (t >= N_NODES * 64) return;
  int n = t >> 6, q = t & 63;
  float2 v = (q < 32) ? *(const float2*)(X + (long)n * 64 + q * 2)
                      : *(const float2*)(Hm + (long)n * 64 + (q - 32) * 2);
  XHb[t] = pk_bf16(v.x, v.y);
}

// out[row] = alpha*(L@src)[row] + beta*other[row]; wave/row, lane = 2 bf16 channels
__global__ __launch_bounds__(256) void k_spmm2b(
    const uint* __restrict__ src, const uint* __restrict__ other,
    float alpha, float beta,
    const int* __restrict__ rptr, const int* __restrict__ cnt,
    const uint* __restrict__ edges, uint* __restrict__ out) {
  int wid = threadIdx.x >> 6, lane = threadIdx.x & 63;
  int row = blockIdx.x * 4 + wid;
  if (row >= N_NODES) return;
  int start = rptr[row], n = cnt[row];
  float ax = 0.f, ay = 0.f;
  for (int base = 0; base < n; base += 64) {
    int rem = n - base;
    int m = rem < 64 ? rem : 64;
    uint rec = (lane < m) ? edges[start + base + lane] : 0u;
    int j = 0;
    for (; j + 4 <= m; j += 4) {
#pragma unroll
      for (int u = 0; u < 4; ++u) {
        uint r = __shfl(rec, j + u);
        int cc = (int)(r >> 16);
        float ww = __uint_as_float(r << 16);
        uint z = src[cc * 64 + lane];
        ax = fmaf(ww, __uint_as_float(z << 16), ax);
        ay = fmaf(ww, __uint_as_float(z & 0xffff0000u), ay);
      }
    }
    for (; j < m; ++j) {
      uint r = __shfl(rec, j);
      int cc = (int)(r >> 16);
      float ww = __uint_as_float(r << 16);
      uint z = src[cc * 64 + lane];
      ax = fmaf(ww, __uint_as_float(z << 16), ax);
      ay = fmaf(ww, __uint_as_float(z & 0xffff0000u), ay);
    }
  }
  float ox = alpha * ax, oy = alpha * ay;
  if (beta != 0.f) {
    uint ov = other[row * 64 + lane];
    ox += beta * __uint_as_float(ov << 16);
    oy += beta * __uint_as_float(ov & 0xffff0000u);
  }
  out[row * 64 + lane] = pk_bf16(ox, oy);
}

// B-frag pack: Bp[((t*16+c)*64+lane)*8+j] = bf16(W[k][col]), k=t*32+(lane>>4)*8+j,
// col = c*16+(lane&15); col = g*64+oc; k-slice s=k/64: even->Wx[g], odd->Wh[g], ord=s>>1
__global__ void k_pack(const float* __restrict__ Wxi, const float* __restrict__ Wxf,
                       const float* __restrict__ Wxc, const float* __restrict__ Wxo,
                       const float* __restrict__ Whi, const float* __restrict__ Whf,
                       const float* __restrict__ Whc, const float* __restrict__ Who,
                       ushort* __restrict__ Bp) {
  int idx = blockIdx.x * blockDim.x + threadIdx.x;
  if (idx >= 12 * 16 * 64 * 8) return;
  int j = idx & 7;
  int lane = (idx >> 3) & 63;
  int c = (idx >> 9) & 15;
  int t = idx >> 13;
  int k = t * 32 + (lane >> 4) * 8 + j;
  int col = c * 16 + (lane & 15);
  int g = col >> 6, oc = col & 63;
  int s = k >> 6, kk = k & 63, ord = s >> 1;
  const float* Wx[4] = {Wxi, Wxf, Wxc, Wxo};
  const float* Wh[4] = {Whi, Whf, Whc, Who};
  const float* W = (s & 1) ? Wh[g] : Wx[g];
  float v = W[(ord * 64 + kk) * 64 + oc];
  __hip_bfloat16 b = __float2bfloat16(v);
  Bp[idx] = *reinterpret_cast<ushort*>(&b);
}

// MFMA GEMM: [XHb|T1b|T2b][N,384] @ W[384,256] + fused LSTM epilogue.
// Block = 4 waves x 16 rows = 64 rows; wave computes 16x256 via 16 16x16x32 tiles.
__global__ __launch_bounds__(256) void k_mfma_lstm(
    const ushort* __restrict__ XHb, const ushort* __restrict__ T1b,
    const ushort* __restrict__ T2b, const float* __restrict__ C,
    const ushort* __restrict__ Bp,
    const float* __restrict__ bxi, const float* __restrict__ bxf,
    const float* __restrict__ bxc, const float* __restrict__ bxo,
    const float* __restrict__ bhi, const float* __restrict__ bhf,
    const float* __restrict__ bhc, const float* __restrict__ bho,
    const float* __restrict__ wci, const float* __restrict__ wcf, const float* __restrict__ wco,
    const float* __restrict__ bi, const float* __restrict__ bf_,
    const float* __restrict__ bc_, const float* __restrict__ bo,
    float* __restrict__ Hout, float* __restrict__ Cout) {
  int lane = threadIdx.x & 63, wid = threadIdx.x >> 6;
  int row0 = blockIdx.x * 64 + wid * 16;
  int arow = row0 + (lane & 15);
  f32x4 acc[16];
#pragma unroll
  for (int c = 0; c < 16; ++c) acc[c] = {0.f, 0.f, 0.f, 0.f};
  const ushort* arrs[3] = {XHb, T1b, T2b};
  for (int t = 0; t < 12; ++t) {
    const ushort* A = arrs[t >> 2];
    int coff = (t & 3) * 32 + (lane >> 4) * 8;
    s8v a = *(const s8v*)(A + (long)arow * 128 + coff);
    const ushort* bp = Bp + (long)t * 8192 + lane * 8;
#pragma unroll
    for (int c = 0; c < 16; ++c) {
      s8v b = *(const s8v*)(bp + c * 512);
      acc[c] = __builtin_amdgcn_mfma_f32_16x16x32_bf16(a, b, acc[c], 0, 0, 0);
    }
  }
  // epilogue: C/D layout col=lane&15 (within tile), row=(lane>>4)*4+reg
  int rbase = row0 + ((lane >> 4) << 2);
  int ocl = lane & 15;
#pragma unroll
  for (int j = 0; j < 4; ++j) {
    int oc = j * 16 + ocl;
    float bI = bxi[oc] + bhi[oc] + bi[oc];
    float bF = bxf[oc] + bhf[oc] + bf_[oc];
    float bT = bxc[oc] + bhc[oc] + bc_[oc];
    float bO = bxo[oc] + bho[oc] + bo[oc];
    float wcI = wci[oc], wcF = wcf[oc], wcO = wco[oc];
#pragma unroll
    for (int r = 0; r < 4; ++r) {
      int row = rbase + r;
      if (row < N_NODES) {
        float cv = C[(long)row * 64 + oc];
        float I = 1.f / (1.f + __expf(-(acc[j][r] + bI + wcI * cv)));
        float F = 1.f / (1.f + __expf(-(acc[4 + j][r] + bF + wcF * cv)));
        float e2 = __expf(2.f * (acc[8 + j][r] + bT));
        float T = 1.f - 2.f / (e2 + 1.f);
        float cn = F * cv + I * T;
        float O = 1.f / (1.f + __expf(-(acc[12 + j][r] + bO + wcO * cn)));
        float e2c = __expf(2.f * cn);
        float tc = 1.f - 2.f / (e2c + 1.f);
        Hout[(long)row * 64 + oc] = O * tc;
        Cout[(long)row * 64 + oc] = cn;
      }
    }
  }
}

extern "C" void kernel_launch(void* const* d_in, const int* in_sizes, int n_in,
                              void* d_out, int out_size, void* d_ws, size_t ws_size,
                              hipStream_t stream) {
  (void)in_sizes; (void)n_in; (void)out_size; (void)ws_size;
  const float* X   = (const float*)d_in[0];
  const int*   ei  = (const int*)d_in[1];
  const float* ew  = (const float*)d_in[2];
  const float* H   = (const float*)d_in[3];
  const float* C   = (const float*)d_in[4];
  const float* Wxi = (const float*)d_in[5];
  const float* bxi = (const float*)d_in[6];
  const float* Wxf = (const float*)d_in[7];
  const float* bxf = (const float*)d_in[8];
  const float* Wxc = (const float*)d_in[9];
  const float* bxc = (const float*)d_in[10];
  const float* Wxo = (const float*)d_in[11];
  const float* bxo = (const float*)d_in[12];
  const float* Whi = (const float*)d_in[13];
  const float* bhi = (const float*)d_in[14];
  const float* Whf = (const float*)d_in[15];
  const float* bhf = (const float*)d_in[16];
  const float* Whc = (const float*)d_in[17];
  const float* bhc = (const float*)d_in[18];
  const float* Who = (const float*)d_in[19];
  const float* bho = (const float*)d_in[20];
  const float* wci = (const float*)d_in[21];
  const float* wcf = (const float*)d_in[22];
  const float* wco = (const float*)d_in[23];
  const float* bi  = (const float*)d_in[24];
  const float* bf_ = (const float*)d_in[25];
  const float* bc_ = (const float*)d_in[26];
  const float* bo  = (const float*)d_in[27];

  float* ws = (float*)d_ws;
  unsigned long long* dc = (unsigned long long*)(ws + O_DC);
  int*    cnt    = (int*)(ws + O_CNT);
  float*  dinv   = ws + O_DINV;
  int*    rptr   = (int*)(ws + O_RPTR);
  ushort* rank   = (ushort*)(ws + O_RANK);
  uint*   edges  = (uint*)(ws + O_EDGE);
  uint*   XHb    = (uint*)(ws + O_XHB);
  uint*   T1b    = (uint*)(ws + O_T1B);
  uint*   T2b    = (uint*)(ws + O_T2B);
  ushort* Bp     = (ushort*)(ws + O_BP);

  float* Hout = (float*)d_out;
  float* Cout = Hout + N_NODES * 64;

  k_zero<<<(100000 + 255) / 256, 256, 0, stream>>>(ws, 100000);
  k_edge_deg<<<2048, 256, 0, stream>>>(ei, ew, dc, rank);
  k_dinv<<<(N_NODES + 255) / 256, 256, 0, stream>>>(dc, cnt, dinv);
  k_scan<<<1, 1024, 0, stream>>>(cnt, rptr);
  k_edge_scatter<<<2048, 256, 0, stream>>>(ei, ew, dinv, rptr, rank, edges);
  k_xhb<<<(N_NODES * 64 + 255) / 256, 256, 0, stream>>>(X, H, XHb);
  k_pack<<<(12 * 16 * 64 * 8 + 255) / 256, 256, 0, stream>>>(Wxi, Wxf, Wxc, Wxo,
                                                             Whi, Whf, Whc, Who, Bp);
  int spmm_grid = (N_NODES + 3) / 4;
  // T1 = L @ XH
  k_spmm2b<<<spmm_grid, 256, 0, stream>>>(XHb, XHb, 1.f, 0.f, rptr, cnt, edges, T1b);
  // T2 = 2 L @ T1 - XH
  k_spmm2b<<<spmm_grid, 256, 0, stream>>>(T1b, XHb, 2.f, -1.f, rptr, cnt, edges, T2b);
  k_mfma_lstm<<<(N_NODES + 63) / 64, 256, 0, stream>>>(
      (const ushort*)XHb, (const ushort*)T1b, (const ushort*)T2b, C, Bp,
      bxi, bxf, bxc, bxo, bhi, bhf, bhc, bho,
      wci, wcf, wco, bi, bf_, bc_, bo, Hout, Cout);
}

// Round 5
// 338.254 us; speedup vs baseline: 3.0703x; 1.0176x over previous
//
#include <hip/hip_runtime.h>
#include <hip/hip_bf16.h>
#include <math.h>

#define N_NODES 50000
#define E_EDGES 1600000
#define NCOPY 8

typedef __attribute__((ext_vector_type(8))) short s8v;    // 8 bf16 frag
typedef __attribute__((ext_vector_type(4))) float f32x4;  // mfma acc

// ---------------- workspace layout (float units) ----------------
#define O_DC8   0                 // 8*50000 u64 (cnt<<40 | fixed24 wsum) = 800000 floats
#define O_CNT   800000
#define O_DINV  850048
#define O_RPTR  900096
#define O_BASE8 950144            // 8*50000 u16 = 200000 floats
#define O_RANK  1150144           // 1.6M u16 (copy<<13 | local rank) = 800000 floats
#define O_EDGE  1950144           // 1.6M packed u32 (col<<16 | bf16(wn))
#define O_XHB   3550144           // 50000*128 bf16 = 3200000 floats
#define O_T1B   6750144
#define O_T2B   9950144
#define O_BP    13150144          // 98304 bf16 = 49152 floats
// end: 13199296 floats ~= 52.8 MB

__device__ __forceinline__ uint pk_bf16(float x, float y) {
  __hip_bfloat16 bx = __float2bfloat16(x), by = __float2bfloat16(y);
  ushort ux = *reinterpret_cast<ushort*>(&bx);
  ushort uy = *reinterpret_cast<ushort*>(&by);
  return ((uint)uy << 16) | (uint)ux;
}

__global__ void k_zero(float* __restrict__ p, int n) {
  int i = blockIdx.x * blockDim.x + threadIdx.x;
  if (i < n) p[i] = 0.f;
}

// one u64 atomic per edge into an 8-way sharded accumulator (shard = bid&7):
// high24 = count, low40 = sum(w * 2^24). Returned count = local rank in shard.
__global__ void k_edge_deg(const int* __restrict__ ei, const float* __restrict__ ew,
                           unsigned long long* __restrict__ dc8,
                           ushort* __restrict__ rank) {
  int copy = blockIdx.x & (NCOPY - 1);
  unsigned long long* dc = dc8 + (long)copy * N_NODES;
  int i = blockIdx.x * blockDim.x + threadIdx.x;
  int stride = gridDim.x * blockDim.x;
  for (int e = i; e < E_EDGES; e += stride) {
    int r = ei[e], c = ei[E_EDGES + e];
    ushort rk = 0;
    if (r != c) {
      unsigned long long pack =
          (1ull << 40) | (unsigned long long)(ew[e] * 16777216.0f + 0.5f);
      unsigned long long old = atomicAdd(&dc[r], pack);
      rk = (ushort)((copy << 13) | (int)(old >> 40));
    }
    rank[e] = rk;
  }
}

// reduce 8 shards: dinv, total cnt, per-shard exclusive base
__global__ void k_dinv(const unsigned long long* __restrict__ dc8,
                       int* __restrict__ cnt, float* __restrict__ dinv,
                       ushort* __restrict__ base8) {
  int i = blockIdx.x * blockDim.x + threadIdx.x;
  if (i < N_NODES) {
    int run = 0;
    unsigned long long s = 0;
#pragma unroll
    for (int j = 0; j < NCOPY; ++j) {
      unsigned long long v = dc8[(long)j * N_NODES + i];
      base8[(long)j * N_NODES + i] = (ushort)run;
      run += (int)(v >> 40);
      s += (v & 0xFFFFFFFFFFull);
    }
    cnt[i] = run;
    float d = (float)s * (1.0f / 16777216.0f);
    dinv[i] = d > 0.f ? rsqrtf(d) : 0.f;
  }
}

// exclusive scan of cnt -> rptr; single block, 1024 threads, shfl-based
__global__ __launch_bounds__(1024) void k_scan(const int* __restrict__ cnt,
                                               int* __restrict__ rptr) {
  __shared__ int wsum[16];
  __shared__ int srun;
  int t = threadIdx.x;
  int lane = t & 63, wid = t >> 6;
  if (t == 0) srun = 0;
  __syncthreads();
  for (int base = 0; base < N_NODES; base += 1024) {
    int i = base + t;
    int v = (i < N_NODES) ? cnt[i] : 0;
    int x = v;
#pragma unroll
    for (int off = 1; off < 64; off <<= 1) {
      int y = __shfl_up(x, off);
      if (lane >= off) x += y;
    }
    if (lane == 63) wsum[wid] = x;
    __syncthreads();
    if (wid == 0) {
      int s = (lane < 16) ? wsum[lane] : 0;
#pragma unroll
      for (int off = 1; off < 16; off <<= 1) {
        int y = __shfl_up(s, off);
        if (lane >= off) s += y;
      }
      if (lane < 16) wsum[lane] = s;
    }
    __syncthreads();
    int woff = (wid > 0) ? wsum[wid - 1] : 0;
    int incl = x + woff;
    int run = srun;
    __syncthreads();
    int excl = incl - v;
    if (i < N_NODES) rptr[i] = run + excl;
    if (t == 1023) srun = run + incl;
    __syncthreads();
  }
}

// atomic-free scatter: pos = rptr[row] + shard_base + local rank
__global__ void k_edge_scatter(const int* __restrict__ ei, const float* __restrict__ ew,
                               const float* __restrict__ dinv,
                               const int* __restrict__ rptr,
                               const ushort* __restrict__ rank,
                               const ushort* __restrict__ base8,
                               uint* __restrict__ edges) {
  int i = blockIdx.x * blockDim.x + threadIdx.x;
  int stride = gridDim.x * blockDim.x;
  for (int e = i; e < E_EDGES; e += stride) {
    int r = ei[e], c = ei[E_EDGES + e];
    if (r != c) {
      float w = -ew[e] * dinv[r] * dinv[c];
      __hip_bfloat16 bw = __float2bfloat16(w);
      ushort uw = *reinterpret_cast<ushort*>(&bw);
      ushort rk = rank[e];
      int copy = (rk >> 13) & 7;
      int pos = rptr[r] + (int)base8[(long)copy * N_NODES + r] + (int)(rk & 8191);
      edges[pos] = ((uint)c << 16) | (uint)uw;
    }
  }
}

// XHb[n] = bf16x2-packed [X[n] | H[n]]  (u32 = 2 channels per thread)
__global__ void k_xhb(const float* __restrict__ X, const float* __restrict__ Hm,
                      uint* __restrict__ XHb) {
  int t = blockIdx.x * blockDim.x + threadIdx.x;
  if (t >= N_NODES * 64) return;
  int n = t >> 6, q = t & 63;
  float2 v = (q < 32) ? *(const float2*)(X + (long)n * 64 + q * 2)
                      : *(const float2*)(Hm + (long)n * 64 + (q - 32) * 2);
  XHb[t] = pk_bf16(v.x, v.y);
}

// out[row] = alpha*(L@src)[row] + beta*other[row]; wave/row, lane = 2 bf16 channels
__global__ __launch_bounds__(256) void k_spmm2b(
    const uint* __restrict__ src, const uint* __restrict__ other,
    float alpha, float beta,
    const int* __restrict__ rptr, const int* __restrict__ cnt,
    const uint* __restrict__ edges, uint* __restrict__ out) {
  int wid = threadIdx.x >> 6, lane = threadIdx.x & 63;
  int row = blockIdx.x * 4 + wid;
  if (row >= N_NODES) return;
  int start = rptr[row], n = cnt[row];
  float ax = 0.f, ay = 0.f;
  for (int base = 0; base < n; base += 64) {
    int rem = n - base;
    int m = rem < 64 ? rem : 64;
    uint rec = (lane < m) ? edges[start + base + lane] : 0u;
    int j = 0;
    for (; j + 4 <= m; j += 4) {
#pragma unroll
      for (int u = 0; u < 4; ++u) {
        uint r = __shfl(rec, j + u);
        int cc = (int)(r >> 16);
        float ww = __uint_as_float(r << 16);
        uint z = src[cc * 64 + lane];
        ax = fmaf(ww, __uint_as_float(z << 16), ax);
        ay = fmaf(ww, __uint_as_float(z & 0xffff0000u), ay);
      }
    }
    for (; j < m; ++j) {
      uint r = __shfl(rec, j);
      int cc = (int)(r >> 16);
      float ww = __uint_as_float(r << 16);
      uint z = src[cc * 64 + lane];
      ax = fmaf(ww, __uint_as_float(z << 16), ax);
      ay = fmaf(ww, __uint_as_float(z & 0xffff0000u), ay);
    }
  }
  float ox = alpha * ax, oy = alpha * ay;
  if (beta != 0.f) {
    uint ov = other[row * 64 + lane];
    ox += beta * __uint_as_float(ov << 16);
    oy += beta * __uint_as_float(ov & 0xffff0000u);
  }
  out[row * 64 + lane] = pk_bf16(ox, oy);
}

// B-frag pack: Bp[((t*16+c)*64+lane)*8+j] = bf16(W[k][col]), k=t*32+(lane>>4)*8+j,
// col = c*16+(lane&15); col = g*64+oc; k-slice s=k/64: even->Wx[g], odd->Wh[g], ord=s>>1
__global__ void k_pack(const float* __restrict__ Wxi, const float* __restrict__ Wxf,
                       const float* __restrict__ Wxc, const float* __restrict__ Wxo,
                       const float* __restrict__ Whi, const float* __restrict__ Whf,
                       const float* __restrict__ Whc, const float* __restrict__ Who,
                       ushort* __restrict__ Bp) {
  int idx = blockIdx.x * blockDim.x + threadIdx.x;
  if (idx >= 12 * 16 * 64 * 8) return;
  int j = idx & 7;
  int lane = (idx >> 3) & 63;
  int c = (idx >> 9) & 15;
  int t = idx >> 13;
  int k = t * 32 + (lane >> 4) * 8 + j;
  int col = c * 16 + (lane & 15);
  int g = col >> 6, oc = col & 63;
  int s = k >> 6, kk = k & 63, ord = s >> 1;
  const float* Wx[4] = {Wxi, Wxf, Wxc, Wxo};
  const float* Wh[4] = {Whi, Whf, Whc, Who};
  const float* W = (s & 1) ? Wh[g] : Wx[g];
  float v = W[(ord * 64 + kk) * 64 + oc];
  __hip_bfloat16 b = __float2bfloat16(v);
  Bp[idx] = *reinterpret_cast<ushort*>(&b);
}

__device__ __forceinline__ float frcp(float x) { return __builtin_amdgcn_rcpf(x); }

// MFMA GEMM: [XHb|T1b|T2b][N,384] @ W[384,256] + fused LSTM epilogue.
// Block = 4 waves x 16 rows = 64 rows; wave computes 16x256 via 16 16x16x32 tiles.
// All 12 A-frags prefetched up-front (one HBM round trip); B is L1-hot.
__global__ __launch_bounds__(256) void k_mfma_lstm(
    const ushort* __restrict__ XHb, const ushort* __restrict__ T1b,
    const ushort* __restrict__ T2b, const float* __restrict__ C,
    const ushort* __restrict__ Bp,
    const float* __restrict__ bxi, const float* __restrict__ bxf,
    const float* __restrict__ bxc, const float* __restrict__ bxo,
    const float* __restrict__ bhi, const float* __restrict__ bhf,
    const float* __restrict__ bhc, const float* __restrict__ bho,
    const float* __restrict__ wci, const float* __restrict__ wcf, const float* __restrict__ wco,
    const float* __restrict__ bi, const float* __restrict__ bf_,
    const float* __restrict__ bc_, const float* __restrict__ bo,
    float* __restrict__ Hout, float* __restrict__ Cout) {
  int lane = threadIdx.x & 63, wid = threadIdx.x >> 6;
  int row0 = blockIdx.x * 64 + wid * 16;
  int ar = row0 + (lane & 15);
  if (ar > N_NODES - 1) ar = N_NODES - 1;  // clamp: dup rows, outputs masked later
  long abase = (long)ar * 128 + (lane >> 4) * 8;
  s8v a[12];
#pragma unroll
  for (int q = 0; q < 4; ++q) a[q] = *(const s8v*)(XHb + abase + q * 32);
#pragma unroll
  for (int q = 0; q < 4; ++q) a[4 + q] = *(const s8v*)(T1b + abase + q * 32);
#pragma unroll
  for (int q = 0; q < 4; ++q) a[8 + q] = *(const s8v*)(T2b + abase + q * 32);
  f32x4 acc[16];
#pragma unroll
  for (int c = 0; c < 16; ++c) acc[c] = {0.f, 0.f, 0.f, 0.f};
  const ushort* bp = Bp + lane * 8;
#pragma unroll
  for (int t = 0; t < 12; ++t) {
#pragma unroll
    for (int c = 0; c < 16; ++c) {
      s8v b = *(const s8v*)(bp + t * 8192 + c * 512);
      acc[c] = __builtin_amdgcn_mfma_f32_16x16x32_bf16(a[t], b, acc[c], 0, 0, 0);
    }
  }
  // epilogue: C/D layout col=lane&15 (within tile), row=(lane>>4)*4+reg
  int rbase = row0 + ((lane >> 4) << 2);
  int ocl = lane & 15;
#pragma unroll
  for (int j = 0; j < 4; ++j) {
    int oc = j * 16 + ocl;
    float bI = bxi[oc] + bhi[oc] + bi[oc];
    float bF = bxf[oc] + bhf[oc] + bf_[oc];
    float bT = bxc[oc] + bhc[oc] + bc_[oc];
    float bO = bxo[oc] + bho[oc] + bo[oc];
    float wcI = wci[oc], wcF = wcf[oc], wcO = wco[oc];
#pragma unroll
    for (int r = 0; r < 4; ++r) {
      int row = rbase + r;
      if (row < N_NODES) {
        float cv = C[(long)row * 64 + oc];
        float I = frcp(1.f + __expf(-(acc[j][r] + bI + wcI * cv)));
        float F = frcp(1.f + __expf(-(acc[4 + j][r] + bF + wcF * cv)));
        float e2 = __expf(2.f * (acc[8 + j][r] + bT));
        float T = 1.f - 2.f * frcp(e2 + 1.f);
        float cn = F * cv + I * T;
        float O = frcp(1.f + __expf(-(acc[12 + j][r] + bO + wcO * cn)));
        float e2c = __expf(2.f * cn);
        float tc = 1.f - 2.f * frcp(e2c + 1.f);
        Hout[(long)row * 64 + oc] = O * tc;
        Cout[(long)row * 64 + oc] = cn;
      }
    }
  }
}

extern "C" void kernel_launch(void* const* d_in, const int* in_sizes, int n_in,
                              void* d_out, int out_size, void* d_ws, size_t ws_size,
                              hipStream_t stream) {
  (void)in_sizes; (void)n_in; (void)out_size; (void)ws_size;
  const float* X   = (const float*)d_in[0];
  const int*   ei  = (const int*)d_in[1];
  const float* ew  = (const float*)d_in[2];
  const float* H   = (const float*)d_in[3];
  const float* C   = (const float*)d_in[4];
  const float* Wxi = (const float*)d_in[5];
  const float* bxi = (const float*)d_in[6];
  const float* Wxf = (const float*)d_in[7];
  const float* bxf = (const float*)d_in[8];
  const float* Wxc = (const float*)d_in[9];
  const float* bxc = (const float*)d_in[10];
  const float* Wxo = (const float*)d_in[11];
  const float* bxo = (const float*)d_in[12];
  const float* Whi = (const float*)d_in[13];
  const float* bhi = (const float*)d_in[14];
  const float* Whf = (const float*)d_in[15];
  const float* bhf = (const float*)d_in[16];
  const float* Whc = (const float*)d_in[17];
  const float* bhc = (const float*)d_in[18];
  const float* Who = (const float*)d_in[19];
  const float* bho = (const float*)d_in[20];
  const float* wci = (const float*)d_in[21];
  const float* wcf = (const float*)d_in[22];
  const float* wco = (const float*)d_in[23];
  const float* bi  = (const float*)d_in[24];
  const float* bf_ = (const float*)d_in[25];
  const float* bc_ = (const float*)d_in[26];
  const float* bo  = (const float*)d_in[27];

  float* ws = (float*)d_ws;
  unsigned long long* dc8 = (unsigned long long*)(ws + O_DC8);
  int*    cnt    = (int*)(ws + O_CNT);
  float*  dinv   = ws + O_DINV;
  int*    rptr   = (int*)(ws + O_RPTR);
  ushort* base8  = (ushort*)(ws + O_BASE8);
  ushort* rank   = (ushort*)(ws + O_RANK);
  uint*   edges  = (uint*)(ws + O_EDGE);
  uint*   XHb    = (uint*)(ws + O_XHB);
  uint*   T1b    = (uint*)(ws + O_T1B);
  uint*   T2b    = (uint*)(ws + O_T2B);
  ushort* Bp     = (ushort*)(ws + O_BP);

  float* Hout = (float*)d_out;
  float* Cout = Hout + N_NODES * 64;

  k_zero<<<(O_CNT + 255) / 256, 256, 0, stream>>>(ws, O_CNT);  // zero dc8 (3.2 MB)
  k_edge_deg<<<2048, 256, 0, stream>>>(ei, ew, dc8, rank);
  k_dinv<<<(N_NODES + 255) / 256, 256, 0, stream>>>(dc8, cnt, dinv, base8);
  k_scan<<<1, 1024, 0, stream>>>(cnt, rptr);
  k_edge_scatter<<<2048, 256, 0, stream>>>(ei, ew, dinv, rptr, rank, base8, edges);
  k_xhb<<<(N_NODES * 64 + 255) / 256, 256, 0, stream>>>(X, H, XHb);
  k_pack<<<(12 * 16 * 64 * 8 + 255) / 256, 256, 0, stream>>>(Wxi, Wxf, Wxc, Wxo,
                                                             Whi, Whf, Whc, Who, Bp);
  int spmm_grid = (N_NODES + 3) / 4;
  // T1 = L @ XH
  k_spmm2b<<<spmm_grid, 256, 0, stream>>>(XHb, XHb, 1.f, 0.f, rptr, cnt, edges, T1b);
  // T2 = 2 L @ T1 - XH
  k_spmm2b<<<spmm_grid, 256, 0, stream>>>(T1b, XHb, 2.f, -1.f, rptr, cnt, edges, T2b);
  k_mfma_lstm<<<(N_NODES + 63) / 64, 256, 0, stream>>>(
      (const ushort*)XHb, (const ushort*)T1b, (const ushort*)T2b, C, Bp,
      bxi, bxf, bxc, bxo, bhi, bhf, bhc, bho,
      wci, wcf, wco, bi, bf_, bc_, bo, Hout, Cout);
}

// Round 6
// 310.017 us; speedup vs baseline: 3.3500x; 1.0911x over previous
//
#include <hip/hip_runtime.h>
#include <hip/hip_bf16.h>
#include <math.h>

#define N_NODES 50000
#define E_EDGES 1600000
#define NCOPY 8

typedef __attribute__((ext_vector_type(8))) short s8v;    // 8 bf16 frag
typedef __attribute__((ext_vector_type(4))) float f32x4;  // mfma acc

// ---------------- workspace layout (float units) ----------------
#define O_DC8   0                 // 8*50000 u64 (cnt<<40 | fixed24 wsum) = 800000 floats
#define O_CNT   800000
#define O_DINV  850048
#define O_RPTR  900096
#define O_BASE8 950144            // 8*50000 u16 = 200000 floats
#define O_RANK  1150144           // 1.6M u16 (copy<<13 | local rank) = 800000 floats
#define O_EDGE  1950144           // 1.6M packed u32 (col<<16 | bf16(wn))
#define O_XHB   3550144           // 50000*128 bf16 = 3200000 floats
#define O_T1B   6750144
#define O_T2B   9950144
#define O_BP    13150144          // 98304 bf16 = 49152 floats
// end: 13199296 floats ~= 52.8 MB

__device__ __forceinline__ uint pk_bf16(float x, float y) {
  __hip_bfloat16 bx = __float2bfloat16(x), by = __float2bfloat16(y);
  ushort ux = *reinterpret_cast<ushort*>(&bx);
  ushort uy = *reinterpret_cast<ushort*>(&by);
  return ((uint)uy << 16) | (uint)ux;
}

__global__ void k_zero(float* __restrict__ p, int n) {
  int i = blockIdx.x * blockDim.x + threadIdx.x;
  if (i < n) p[i] = 0.f;
}

// one u64 atomic per edge into an 8-way sharded accumulator (shard = bid&7):
// high24 = count, low40 = sum(w * 2^24). Returned count = local rank in shard.
__global__ void k_edge_deg(const int* __restrict__ ei, const float* __restrict__ ew,
                           unsigned long long* __restrict__ dc8,
                           ushort* __restrict__ rank) {
  int copy = blockIdx.x & (NCOPY - 1);
  unsigned long long* dc = dc8 + (long)copy * N_NODES;
  int i = blockIdx.x * blockDim.x + threadIdx.x;
  int stride = gridDim.x * blockDim.x;
  for (int e = i; e < E_EDGES; e += stride) {
    int r = ei[e], c = ei[E_EDGES + e];
    ushort rk = 0;
    if (r != c) {
      unsigned long long pack =
          (1ull << 40) | (unsigned long long)(ew[e] * 16777216.0f + 0.5f);
      unsigned long long old = atomicAdd(&dc[r], pack);
      rk = (ushort)((copy << 13) | (int)(old >> 40));
    }
    rank[e] = rk;
  }
}

// reduce 8 shards: dinv, total cnt, per-shard exclusive base
__global__ void k_dinv(const unsigned long long* __restrict__ dc8,
                       int* __restrict__ cnt, float* __restrict__ dinv,
                       ushort* __restrict__ base8) {
  int i = blockIdx.x * blockDim.x + threadIdx.x;
  if (i < N_NODES) {
    int run = 0;
    unsigned long long s = 0;
#pragma unroll
    for (int j = 0; j < NCOPY; ++j) {
      unsigned long long v = dc8[(long)j * N_NODES + i];
      base8[(long)j * N_NODES + i] = (ushort)run;
      run += (int)(v >> 40);
      s += (v & 0xFFFFFFFFFFull);
    }
    cnt[i] = run;
    float d = (float)s * (1.0f / 16777216.0f);
    dinv[i] = d > 0.f ? rsqrtf(d) : 0.f;
  }
}

// exclusive scan of cnt -> rptr; single block, 1024 threads, shfl-based
__global__ __launch_bounds__(1024) void k_scan(const int* __restrict__ cnt,
                                               int* __restrict__ rptr) {
  __shared__ int wsum[16];
  __shared__ int srun;
  int t = threadIdx.x;
  int lane = t & 63, wid = t >> 6;
  if (t == 0) srun = 0;
  __syncthreads();
  for (int base = 0; base < N_NODES; base += 1024) {
    int i = base + t;
    int v = (i < N_NODES) ? cnt[i] : 0;
    int x = v;
#pragma unroll
    for (int off = 1; off < 64; off <<= 1) {
      int y = __shfl_up(x, off);
      if (lane >= off) x += y;
    }
    if (lane == 63) wsum[wid] = x;
    __syncthreads();
    if (wid == 0) {
      int s = (lane < 16) ? wsum[lane] : 0;
#pragma unroll
      for (int off = 1; off < 16; off <<= 1) {
        int y = __shfl_up(s, off);
        if (lane >= off) s += y;
      }
      if (lane < 16) wsum[lane] = s;
    }
    __syncthreads();
    int woff = (wid > 0) ? wsum[wid - 1] : 0;
    int incl = x + woff;
    int run = srun;
    __syncthreads();
    int excl = incl - v;
    if (i < N_NODES) rptr[i] = run + excl;
    if (t == 1023) srun = run + incl;
    __syncthreads();
  }
}

// atomic-free scatter: pos = rptr[row] + shard_base + local rank
__global__ void k_edge_scatter(const int* __restrict__ ei, const float* __restrict__ ew,
                               const float* __restrict__ dinv,
                               const int* __restrict__ rptr,
                               const ushort* __restrict__ rank,
                               const ushort* __restrict__ base8,
                               uint* __restrict__ edges) {
  int i = blockIdx.x * blockDim.x + threadIdx.x;
  int stride = gridDim.x * blockDim.x;
  for (int e = i; e < E_EDGES; e += stride) {
    int r = ei[e], c = ei[E_EDGES + e];
    if (r != c) {
      float w = -ew[e] * dinv[r] * dinv[c];
      __hip_bfloat16 bw = __float2bfloat16(w);
      ushort uw = *reinterpret_cast<ushort*>(&bw);
      ushort rk = rank[e];
      int copy = (rk >> 13) & 7;
      int pos = rptr[r] + (int)base8[(long)copy * N_NODES + r] + (int)(rk & 8191);
      edges[pos] = ((uint)c << 16) | (uint)uw;
    }
  }
}

// XHb[n] = bf16x2-packed [X[n] | H[n]]  (u32 = 2 channels per thread)
__global__ void k_xhb(const float* __restrict__ X, const float* __restrict__ Hm,
                      uint* __restrict__ XHb) {
  int t = blockIdx.x * blockDim.x + threadIdx.x;
  if (t >= N_NODES * 64) return;
  int n = t >> 6, q = t & 63;
  float2 v = (q < 32) ? *(const float2*)(X + (long)n * 64 + q * 2)
                      : *(const float2*)(Hm + (long)n * 64 + (q - 32) * 2);
  XHb[t] = pk_bf16(v.x, v.y);
}

// out[row] = alpha*(L@src)[row] + beta*other[row]; wave/row, lane = 2 bf16 channels
__global__ __launch_bounds__(256) void k_spmm2b(
    const uint* __restrict__ src, const uint* __restrict__ other,
    float alpha, float beta,
    const int* __restrict__ rptr, const int* __restrict__ cnt,
    const uint* __restrict__ edges, uint* __restrict__ out) {
  int wid = threadIdx.x >> 6, lane = threadIdx.x & 63;
  int row = blockIdx.x * 4 + wid;
  if (row >= N_NODES) return;
  int start = rptr[row], n = cnt[row];
  float ax = 0.f, ay = 0.f;
  for (int base = 0; base < n; base += 64) {
    int rem = n - base;
    int m = rem < 64 ? rem : 64;
    uint rec = (lane < m) ? edges[start + base + lane] : 0u;
    int j = 0;
    for (; j + 4 <= m; j += 4) {
#pragma unroll
      for (int u = 0; u < 4; ++u) {
        uint r = __shfl(rec, j + u);
        int cc = (int)(r >> 16);
        float ww = __uint_as_float(r << 16);
        uint z = src[cc * 64 + lane];
        ax = fmaf(ww, __uint_as_float(z << 16), ax);
        ay = fmaf(ww, __uint_as_float(z & 0xffff0000u), ay);
      }
    }
    for (; j < m; ++j) {
      uint r = __shfl(rec, j);
      int cc = (int)(r >> 16);
      float ww = __uint_as_float(r << 16);
      uint z = src[cc * 64 + lane];
      ax = fmaf(ww, __uint_as_float(z << 16), ax);
      ay = fmaf(ww, __uint_as_float(z & 0xffff0000u), ay);
    }
  }
  float ox = alpha * ax, oy = alpha * ay;
  if (beta != 0.f) {
    uint ov = other[row * 64 + lane];
    ox += beta * __uint_as_float(ov << 16);
    oy += beta * __uint_as_float(ov & 0xffff0000u);
  }
  out[row * 64 + lane] = pk_bf16(ox, oy);
}

// B-frag pack: Bp[((t*16+c)*64+lane)*8+j] = bf16(W[k][col]), k=t*32+(lane>>4)*8+j,
// col = c*16+(lane&15); col = g*64+oc; k-slice s=k/64: even->Wx[g], odd->Wh[g], ord=s>>1
__global__ void k_pack(const float* __restrict__ Wxi, const float* __restrict__ Wxf,
                       const float* __restrict__ Wxc, const float* __restrict__ Wxo,
                       const float* __restrict__ Whi, const float* __restrict__ Whf,
                       const float* __restrict__ Whc, const float* __restrict__ Who,
                       ushort* __restrict__ Bp) {
  int idx = blockIdx.x * blockDim.x + threadIdx.x;
  if (idx >= 12 * 16 * 64 * 8) return;
  int j = idx & 7;
  int lane = (idx >> 3) & 63;
  int c = (idx >> 9) & 15;
  int t = idx >> 13;
  int k = t * 32 + (lane >> 4) * 8 + j;
  int col = c * 16 + (lane & 15);
  int g = col >> 6, oc = col & 63;
  int s = k >> 6, kk = k & 63, ord = s >> 1;
  const float* Wx[4] = {Wxi, Wxf, Wxc, Wxo};
  const float* Wh[4] = {Whi, Whf, Whc, Who};
  const float* W = (s & 1) ? Wh[g] : Wx[g];
  float v = W[(ord * 64 + kk) * 64 + oc];
  __hip_bfloat16 b = __float2bfloat16(v);
  Bp[idx] = *reinterpret_cast<ushort*>(&b);
}

__device__ __forceinline__ float frcp(float x) { return __builtin_amdgcn_rcpf(x); }

// MFMA GEMM: [XHb|T1b|T2b][N,384] @ W[384,256] + fused LSTM epilogue.
// Block = 4 waves x 16 rows = 64 rows; wave computes 16x256 via 16 16x16x32 tiles.
// A: all 12 frags prefetched (one HBM round trip).
// B: per-t 16 KB tile staged to LDS via global_load_lds, double-buffered;
//    stage of t+1 issued right after the barrier so the DMA overlaps step t's
//    ds_read+MFMA, and the next barrier's vmcnt(0) is the completion wait.
__global__ __launch_bounds__(256) void k_mfma_lstm(
    const ushort* __restrict__ XHb, const ushort* __restrict__ T1b,
    const ushort* __restrict__ T2b, const float* __restrict__ C,
    const ushort* __restrict__ Bp,
    const float* __restrict__ bxi, const float* __restrict__ bxf,
    const float* __restrict__ bxc, const float* __restrict__ bxo,
    const float* __restrict__ bhi, const float* __restrict__ bhf,
    const float* __restrict__ bhc, const float* __restrict__ bho,
    const float* __restrict__ wci, const float* __restrict__ wcf, const float* __restrict__ wco,
    const float* __restrict__ bi, const float* __restrict__ bf_,
    const float* __restrict__ bc_, const float* __restrict__ bo,
    float* __restrict__ Hout, float* __restrict__ Cout) {
  __shared__ ushort bsh[2][8192];  // 2 x 16 KB B tiles
  int lane = threadIdx.x & 63, wid = threadIdx.x >> 6;
  int row0 = blockIdx.x * 64 + wid * 16;
  int ar = row0 + (lane & 15);
  if (ar > N_NODES - 1) ar = N_NODES - 1;  // clamp: dup rows, outputs masked later
  long abase = (long)ar * 128 + (lane >> 4) * 8;

  // stage helper: tile t -> bsh[buf]; 16 segments of 64 lanes x 16 B
#define STAGE(buf, t)                                                          \
  {                                                                            \
    _Pragma("unroll") for (int q = 0; q < 4; ++q) {                            \
      int seg = wid * 4 + q;                                                   \
      __builtin_amdgcn_global_load_lds(                                        \
          (const __attribute__((address_space(1))) uint*)(Bp + (t)*8192 +     \
                                                          seg * 512 + lane * 8),\
          (__attribute__((address_space(3))) uint*)&bsh[buf][seg * 512],       \
          16, 0, 0);                                                           \
    }                                                                          \
  }

  STAGE(0, 0)

  s8v a[12];
#pragma unroll
  for (int q = 0; q < 4; ++q) a[q] = *(const s8v*)(XHb + abase + q * 32);
#pragma unroll
  for (int q = 0; q < 4; ++q) a[4 + q] = *(const s8v*)(T1b + abase + q * 32);
#pragma unroll
  for (int q = 0; q < 4; ++q) a[8 + q] = *(const s8v*)(T2b + abase + q * 32);

  f32x4 acc[16];
#pragma unroll
  for (int c = 0; c < 16; ++c) acc[c] = {0.f, 0.f, 0.f, 0.f};

#pragma unroll
  for (int t = 0; t < 12; ++t) {
    int buf = t & 1;
    __syncthreads();               // vmcnt(0): stage(t) landed; prev reads done
    if (t < 11) STAGE(buf ^ 1, t + 1)
    const ushort* bp = &bsh[buf][lane * 8];
#pragma unroll
    for (int c = 0; c < 16; ++c) {
      s8v b = *(const s8v*)(bp + c * 512);
      acc[c] = __builtin_amdgcn_mfma_f32_16x16x32_bf16(a[t], b, acc[c], 0, 0, 0);
    }
  }
#undef STAGE

  // epilogue: C/D layout col=lane&15 (within tile), row=(lane>>4)*4+reg
  int rbase = row0 + ((lane >> 4) << 2);
  int ocl = lane & 15;
#pragma unroll
  for (int j = 0; j < 4; ++j) {
    int oc = j * 16 + ocl;
    float bI = bxi[oc] + bhi[oc] + bi[oc];
    float bF = bxf[oc] + bhf[oc] + bf_[oc];
    float bT = bxc[oc] + bhc[oc] + bc_[oc];
    float bO = bxo[oc] + bho[oc] + bo[oc];
    float wcI = wci[oc], wcF = wcf[oc], wcO = wco[oc];
#pragma unroll
    for (int r = 0; r < 4; ++r) {
      int row = rbase + r;
      if (row < N_NODES) {
        float cv = C[(long)row * 64 + oc];
        float I = frcp(1.f + __expf(-(acc[j][r] + bI + wcI * cv)));
        float F = frcp(1.f + __expf(-(acc[4 + j][r] + bF + wcF * cv)));
        float e2 = __expf(2.f * (acc[8 + j][r] + bT));
        float T = 1.f - 2.f * frcp(e2 + 1.f);
        float cn = F * cv + I * T;
        float O = frcp(1.f + __expf(-(acc[12 + j][r] + bO + wcO * cn)));
        float e2c = __expf(2.f * cn);
        float tc = 1.f - 2.f * frcp(e2c + 1.f);
        Hout[(long)row * 64 + oc] = O * tc;
        Cout[(long)row * 64 + oc] = cn;
      }
    }
  }
}

extern "C" void kernel_launch(void* const* d_in, const int* in_sizes, int n_in,
                              void* d_out, int out_size, void* d_ws, size_t ws_size,
                              hipStream_t stream) {
  (void)in_sizes; (void)n_in; (void)out_size; (void)ws_size;
  const float* X   = (const float*)d_in[0];
  const int*   ei  = (const int*)d_in[1];
  const float* ew  = (const float*)d_in[2];
  const float* H   = (const float*)d_in[3];
  const float* C   = (const float*)d_in[4];
  const float* Wxi = (const float*)d_in[5];
  const float* bxi = (const float*)d_in[6];
  const float* Wxf = (const float*)d_in[7];
  const float* bxf = (const float*)d_in[8];
  const float* Wxc = (const float*)d_in[9];
  const float* bxc = (const float*)d_in[10];
  const float* Wxo = (const float*)d_in[11];
  const float* bxo = (const float*)d_in[12];
  const float* Whi = (const float*)d_in[13];
  const float* bhi = (const float*)d_in[14];
  const float* Whf = (const float*)d_in[15];
  const float* bhf = (const float*)d_in[16];
  const float* Whc = (const float*)d_in[17];
  const float* bhc = (const float*)d_in[18];
  const float* Who = (const float*)d_in[19];
  const float* bho = (const float*)d_in[20];
  const float* wci = (const float*)d_in[21];
  const float* wcf = (const float*)d_in[22];
  const float* wco = (const float*)d_in[23];
  const float* bi  = (const float*)d_in[24];
  const float* bf_ = (const float*)d_in[25];
  const float* bc_ = (const float*)d_in[26];
  const float* bo  = (const float*)d_in[27];

  float* ws = (float*)d_ws;
  unsigned long long* dc8 = (unsigned long long*)(ws + O_DC8);
  int*    cnt    = (int*)(ws + O_CNT);
  float*  dinv   = ws + O_DINV;
  int*    rptr   = (int*)(ws + O_RPTR);
  ushort* base8  = (ushort*)(ws + O_BASE8);
  ushort* rank   = (ushort*)(ws + O_RANK);
  uint*   edges  = (uint*)(ws + O_EDGE);
  uint*   XHb    = (uint*)(ws + O_XHB);
  uint*   T1b    = (uint*)(ws + O_T1B);
  uint*   T2b    = (uint*)(ws + O_T2B);
  ushort* Bp     = (ushort*)(ws + O_BP);

  float* Hout = (float*)d_out;
  float* Cout = Hout + N_NODES * 64;

  k_zero<<<(O_CNT + 255) / 256, 256, 0, stream>>>(ws, O_CNT);  // zero dc8 (3.2 MB)
  k_edge_deg<<<2048, 256, 0, stream>>>(ei, ew, dc8, rank);
  k_dinv<<<(N_NODES + 255) / 256, 256, 0, stream>>>(dc8, cnt, dinv, base8);
  k_scan<<<1, 1024, 0, stream>>>(cnt, rptr);
  k_edge_scatter<<<2048, 256, 0, stream>>>(ei, ew, dinv, rptr, rank, base8, edges);
  k_xhb<<<(N_NODES * 64 + 255) / 256, 256, 0, stream>>>(X, H, XHb);
  k_pack<<<(12 * 16 * 64 * 8 + 255) / 256, 256, 0, stream>>>(Wxi, Wxf, Wxc, Wxo,
                                                             Whi, Whf, Whc, Who, Bp);
  int spmm_grid = (N_NODES + 3) / 4;
  // T1 = L @ XH
  k_spmm2b<<<spmm_grid, 256, 0, stream>>>(XHb, XHb, 1.f, 0.f, rptr, cnt, edges, T1b);
  // T2 = 2 L @ T1 - XH
  k_spmm2b<<<spmm_grid, 256, 0, stream>>>(T1b, XHb, 2.f, -1.f, rptr, cnt, edges, T2b);
  k_mfma_lstm<<<(N_NODES + 63) / 64, 256, 0, stream>>>(
      (const ushort*)XHb, (const ushort*)T1b, (const ushort*)T2b, C, Bp,
      bxi, bxf, bxc, bxo, bhi, bhf, bhc, bho,
      wci, wcf, wco, bi, bf_, bc_, bo, Hout, Cout);
}

// Round 7
// 288.780 us; speedup vs baseline: 3.5963x; 1.0735x over previous
//
#include <hip/hip_runtime.h>
#include <hip/hip_bf16.h>
#include <math.h>

#define N_NODES 50000
#define E_EDGES 1600000
#define NBKT 196          // row buckets of 256 rows
#define PBLK 400          // blocks in hist/scatter phases
#define CHUNK 4000        // edges per block (PBLK*CHUNK == E_EDGES)

typedef __attribute__((ext_vector_type(8))) short s8v;    // 8 bf16 frag
typedef __attribute__((ext_vector_type(4))) float f32x4;  // mfma acc

// ---------------- workspace layout (float units) ----------------
#define O_BLKH  0          // 196*400 u32, scanned in-place
#define O_BBASE 78592      // 197 u32 bucket bases
#define O_CNT   78848      // 50000 i32
#define O_DINV  128896     // 50000 f32
#define O_RPTR  178944     // 50000 i32
#define O_SREC  228992     // 1.6M u64 records = 3.2M floats
#define O_SREC2 3428992    // 1.6M u64 sorted records
#define O_EDGE  O_SREC     // alias: final u32 edges (srec dead after k_csr)
#define O_XHB   O_SREC2    // alias: XHb written after k_finalize (srec2 dead)
#define O_T1B   6628992
#define O_T2B   9828992
#define O_BP    13028992   // 98304 bf16
// end: 13078144 floats ~= 52.3 MB

__device__ __forceinline__ uint pk_bf16(float x, float y) {
  __hip_bfloat16 bx = __float2bfloat16(x), by = __float2bfloat16(y);
  ushort ux = *reinterpret_cast<ushort*>(&bx);
  ushort uy = *reinterpret_cast<ushort*>(&by);
  return ((uint)uy << 16) | (uint)ux;
}

// ---- phase 1: per-block bucket histogram (no global atomics) ----
__global__ __launch_bounds__(256) void k_hist(const int* __restrict__ ei,
                                              uint* __restrict__ blkh) {
  __shared__ uint h[NBKT];
  int blk = blockIdx.x, tid = threadIdx.x;
  for (int i = tid; i < NBKT; i += 256) h[i] = 0;
  __syncthreads();
  int e0 = blk * CHUNK;
  for (int i = tid; i < CHUNK; i += 256) {
    int e = e0 + i;
    int r = ei[e], c = ei[E_EDGES + e];
    if (r != c) atomicAdd(&h[r >> 8], 1u);
  }
  __syncthreads();
  for (int i = tid; i < NBKT; i += 256) blkh[i * PBLK + blk] = h[i];  // [bucket][block]
}

// ---- phase 2: exclusive scan of 78400 (bucket,block) counts, in place; emit bases ----
__global__ __launch_bounds__(1024) void k_scan_g(uint* __restrict__ a,
                                                 uint* __restrict__ bbase) {
  const int n = NBKT * PBLK;
  __shared__ uint wsum[16];
  __shared__ uint srun;
  int t = threadIdx.x;
  int lane = t & 63, wid = t >> 6;
  if (t == 0) srun = 0;
  __syncthreads();
  for (int base = 0; base < n; base += 1024) {
    int i = base + t;
    uint v = (i < n) ? a[i] : 0u;
    uint x = v;
#pragma unroll
    for (int off = 1; off < 64; off <<= 1) {
      uint y = __shfl_up(x, off);
      if (lane >= off) x += y;
    }
    if (lane == 63) wsum[wid] = x;
    __syncthreads();
    if (wid == 0) {
      uint s = (lane < 16) ? wsum[lane] : 0u;
#pragma unroll
      for (int off = 1; off < 16; off <<= 1) {
        uint y = __shfl_up(s, off);
        if (lane >= off) s += y;
      }
      if (lane < 16) wsum[lane] = s;
    }
    __syncthreads();
    uint woff = (wid > 0) ? wsum[wid - 1] : 0u;
    uint incl = x + woff;
    uint run = srun;
    __syncthreads();
    if (i < n) a[i] = run + incl - v;  // exclusive
    if (t == 1023) srun = run + incl;
    __syncthreads();
  }
  if (t < NBKT) bbase[t] = a[t * PBLK];
  if (t == NBKT) bbase[NBKT] = srun;
}

// ---- phase 3: scatter edges to bucket-contiguous u64 records via LDS cursors ----
__global__ __launch_bounds__(256) void k_scatter_b(const int* __restrict__ ei,
                                                   const float* __restrict__ ew,
                                                   const uint* __restrict__ off,
                                                   unsigned long long* __restrict__ srec) {
  __shared__ uint cur[NBKT];
  int blk = blockIdx.x, tid = threadIdx.x;
  for (int i = tid; i < NBKT; i += 256) cur[i] = off[i * PBLK + blk];
  __syncthreads();
  int e0 = blk * CHUNK;
  for (int i = tid; i < CHUNK; i += 256) {
    int e = e0 + i;
    int r = ei[e], c = ei[E_EDGES + e];
    if (r != c) {
      uint pos = atomicAdd(&cur[r >> 8], 1u);
      srec[pos] = ((unsigned long long)(r & 255) << 48) |
                  ((unsigned long long)(uint)c << 32) |
                  (unsigned long long)__float_as_uint(ew[e]);
    }
  }
}

// ---- phase 4: per-bucket CSR build + degree/dinv (LDS atomics only) ----
__global__ __launch_bounds__(256) void k_csr(const unsigned long long* __restrict__ srec,
                                             const uint* __restrict__ bbase,
                                             unsigned long long* __restrict__ srec2,
                                             int* __restrict__ cnt, float* __restrict__ dinv,
                                             int* __restrict__ rptr) {
  __shared__ uint hc[256], hs[256], cur[256], wsum[4];
  int b = blockIdx.x, t = threadIdx.x;
  uint start = bbase[b], endv = bbase[b + 1];
  hc[t] = 0; hs[t] = 0;
  __syncthreads();
  for (uint i = start + t; i < endv; i += 256) {
    unsigned long long rec = srec[i];
    int rl = (int)(rec >> 48);
    float w = __uint_as_float((uint)rec);
    atomicAdd(&hc[rl], 1u);
    atomicAdd(&hs[rl], (uint)(w * 1048576.0f + 0.5f));  // fixed 2^20
  }
  __syncthreads();
  int lane = t & 63, wid = t >> 6;
  uint myc = hc[t];
  uint x = myc;
#pragma unroll
  for (int off = 1; off < 64; off <<= 1) {
    uint y = __shfl_up(x, off);
    if (lane >= off) x += y;
  }
  if (lane == 63) wsum[wid] = x;
  __syncthreads();
  uint woff = 0;
#pragma unroll
  for (int j = 0; j < 4; ++j) if (j < wid) woff += wsum[j];
  uint excl = woff + x - myc;
  int row = b * 256 + t;
  if (row < N_NODES) {
    float d = (float)hs[t] * (1.0f / 1048576.0f);
    dinv[row] = d > 0.f ? rsqrtf(d) : 0.f;
    cnt[row] = (int)myc;
    rptr[row] = (int)(start + excl);
  }
  cur[t] = start + excl;
  __syncthreads();
  for (uint i = start + t; i < endv; i += 256) {
    unsigned long long rec = srec[i];
    int rl = (int)(rec >> 48);
    uint pos = atomicAdd(&cur[rl], 1u);
    srec2[pos] = rec;
  }
}

// ---- phase 5: fold dinv into weights, emit final u32 edge records ----
__global__ __launch_bounds__(256) void k_finalize(const unsigned long long* __restrict__ srec2,
                                                  const uint* __restrict__ bbase,
                                                  const float* __restrict__ dinv,
                                                  uint* __restrict__ edges) {
  int b = blockIdx.x, t = threadIdx.x;
  uint start = bbase[b], endv = bbase[b + 1];
  for (uint i = start + t; i < endv; i += 256) {
    unsigned long long rec = srec2[i];
    int rl = (int)(rec >> 48);
    int c = (int)((rec >> 32) & 0xffff);
    float w = __uint_as_float((uint)rec);
    int r = b * 256 + rl;
    float wn = -w * dinv[r] * dinv[c];
    __hip_bfloat16 bw = __float2bfloat16(wn);
    edges[i] = ((uint)c << 16) | (uint)*reinterpret_cast<ushort*>(&bw);
  }
}

// XHb[n] = bf16x2-packed [X[n] | H[n]]  (u32 = 2 channels per thread)
__global__ void k_xhb(const float* __restrict__ X, const float* __restrict__ Hm,
                      uint* __restrict__ XHb) {
  int t = blockIdx.x * blockDim.x + threadIdx.x;
  if (t >= N_NODES * 64) return;
  int n = t >> 6, q = t & 63;
  float2 v = (q < 32) ? *(const float2*)(X + (long)n * 64 + q * 2)
                      : *(const float2*)(Hm + (long)n * 64 + (q - 32) * 2);
  XHb[t] = pk_bf16(v.x, v.y);
}

// out[row] = alpha*(L@src)[row] + beta*other[row]; wave/row, lane = 2 bf16 channels
__global__ __launch_bounds__(256) void k_spmm2b(
    const uint* __restrict__ src, const uint* __restrict__ other,
    float alpha, float beta,
    const int* __restrict__ rptr, const int* __restrict__ cnt,
    const uint* __restrict__ edges, uint* __restrict__ out) {
  int wid = threadIdx.x >> 6, lane = threadIdx.x & 63;
  int row = blockIdx.x * 4 + wid;
  if (row >= N_NODES) return;
  int start = rptr[row], n = cnt[row];
  float ax = 0.f, ay = 0.f;
  for (int base = 0; base < n; base += 64) {
    int rem = n - base;
    int m = rem < 64 ? rem : 64;
    uint rec = (lane < m) ? edges[start + base + lane] : 0u;
    int j = 0;
    for (; j + 4 <= m; j += 4) {
#pragma unroll
      for (int u = 0; u < 4; ++u) {
        uint r = __shfl(rec, j + u);
        int cc = (int)(r >> 16);
        float ww = __uint_as_float(r << 16);
        uint z = src[cc * 64 + lane];
        ax = fmaf(ww, __uint_as_float(z << 16), ax);
        ay = fmaf(ww, __uint_as_float(z & 0xffff0000u), ay);
      }
    }
    for (; j < m; ++j) {
      uint r = __shfl(rec, j);
      int cc = (int)(r >> 16);
      float ww = __uint_as_float(r << 16);
      uint z = src[cc * 64 + lane];
      ax = fmaf(ww, __uint_as_float(z << 16), ax);
      ay = fmaf(ww, __uint_as_float(z & 0xffff0000u), ay);
    }
  }
  float ox = alpha * ax, oy = alpha * ay;
  if (beta != 0.f) {
    uint ov = other[row * 64 + lane];
    ox += beta * __uint_as_float(ov << 16);
    oy += beta * __uint_as_float(ov & 0xffff0000u);
  }
  out[row * 64 + lane] = pk_bf16(ox, oy);
}

// B-frag pack: Bp[((t*16+c)*64+lane)*8+j] = bf16(W[k][col]), k=t*32+(lane>>4)*8+j,
// col = c*16+(lane&15); col = g*64+oc; k-slice s=k/64: even->Wx[g], odd->Wh[g], ord=s>>1
__global__ void k_pack(const float* __restrict__ Wxi, const float* __restrict__ Wxf,
                       const float* __restrict__ Wxc, const float* __restrict__ Wxo,
                       const float* __restrict__ Whi, const float* __restrict__ Whf,
                       const float* __restrict__ Whc, const float* __restrict__ Who,
                       ushort* __restrict__ Bp) {
  int idx = blockIdx.x * blockDim.x + threadIdx.x;
  if (idx >= 12 * 16 * 64 * 8) return;
  int j = idx & 7;
  int lane = (idx >> 3) & 63;
  int c = (idx >> 9) & 15;
  int t = idx >> 13;
  int k = t * 32 + (lane >> 4) * 8 + j;
  int col = c * 16 + (lane & 15);
  int g = col >> 6, oc = col & 63;
  int s = k >> 6, kk = k & 63, ord = s >> 1;
  const float* Wx[4] = {Wxi, Wxf, Wxc, Wxo};
  const float* Wh[4] = {Whi, Whf, Whc, Who};
  const float* W = (s & 1) ? Wh[g] : Wx[g];
  float v = W[(ord * 64 + kk) * 64 + oc];
  __hip_bfloat16 b = __float2bfloat16(v);
  Bp[idx] = *reinterpret_cast<ushort*>(&b);
}

__device__ __forceinline__ float frcp(float x) { return __builtin_amdgcn_rcpf(x); }

// MFMA GEMM: [XHb|T1b|T2b][N,384] @ W[384,256] + fused LSTM epilogue.
// Block = 4 waves x 16 rows = 64 rows; wave computes 16x256 via 16 16x16x32 tiles.
// A: all 12 frags prefetched. B: LDS double-buffered via global_load_lds.
__global__ __launch_bounds__(256) void k_mfma_lstm(
    const ushort* __restrict__ XHb, const ushort* __restrict__ T1b,
    const ushort* __restrict__ T2b, const float* __restrict__ C,
    const ushort* __restrict__ Bp,
    const float* __restrict__ bxi, const float* __restrict__ bxf,
    const float* __restrict__ bxc, const float* __restrict__ bxo,
    const float* __restrict__ bhi, const float* __restrict__ bhf,
    const float* __restrict__ bhc, const float* __restrict__ bho,
    const float* __restrict__ wci, const float* __restrict__ wcf, const float* __restrict__ wco,
    const float* __restrict__ bi, const float* __restrict__ bf_,
    const float* __restrict__ bc_, const float* __restrict__ bo,
    float* __restrict__ Hout, float* __restrict__ Cout) {
  __shared__ ushort bsh[2][8192];  // 2 x 16 KB B tiles
  int lane = threadIdx.x & 63, wid = threadIdx.x >> 6;
  int row0 = blockIdx.x * 64 + wid * 16;
  int ar = row0 + (lane & 15);
  if (ar > N_NODES - 1) ar = N_NODES - 1;  // clamp: dup rows, outputs masked later
  long abase = (long)ar * 128 + (lane >> 4) * 8;

#define STAGE(buf, t)                                                          \
  {                                                                            \
    _Pragma("unroll") for (int q = 0; q < 4; ++q) {                            \
      int seg = wid * 4 + q;                                                   \
      __builtin_amdgcn_global_load_lds(                                        \
          (const __attribute__((address_space(1))) uint*)(Bp + (t)*8192 +     \
                                                          seg * 512 + lane * 8),\
          (__attribute__((address_space(3))) uint*)&bsh[buf][seg * 512],       \
          16, 0, 0);                                                           \
    }                                                                          \
  }

  STAGE(0, 0)

  s8v a[12];
#pragma unroll
  for (int q = 0; q < 4; ++q) a[q] = *(const s8v*)(XHb + abase + q * 32);
#pragma unroll
  for (int q = 0; q < 4; ++q) a[4 + q] = *(const s8v*)(T1b + abase + q * 32);
#pragma unroll
  for (int q = 0; q < 4; ++q) a[8 + q] = *(const s8v*)(T2b + abase + q * 32);

  f32x4 acc[16];
#pragma unroll
  for (int c = 0; c < 16; ++c) acc[c] = {0.f, 0.f, 0.f, 0.f};

#pragma unroll
  for (int t = 0; t < 12; ++t) {
    int buf = t & 1;
    __syncthreads();
    if (t < 11) STAGE(buf ^ 1, t + 1)
    const ushort* bp = &bsh[buf][lane * 8];
#pragma unroll
    for (int c = 0; c < 16; ++c) {
      s8v b = *(const s8v*)(bp + c * 512);
      acc[c] = __builtin_amdgcn_mfma_f32_16x16x32_bf16(a[t], b, acc[c], 0, 0, 0);
    }
  }
#undef STAGE

  int rbase = row0 + ((lane >> 4) << 2);
  int ocl = lane & 15;
#pragma unroll
  for (int j = 0; j < 4; ++j) {
    int oc = j * 16 + ocl;
    float bI = bxi[oc] + bhi[oc] + bi[oc];
    float bF = bxf[oc] + bhf[oc] + bf_[oc];
    float bT = bxc[oc] + bhc[oc] + bc_[oc];
    float bO = bxo[oc] + bho[oc] + bo[oc];
    float wcI = wci[oc], wcF = wcf[oc], wcO = wco[oc];
#pragma unroll
    for (int r = 0; r < 4; ++r) {
      int row = rbase + r;
      if (row < N_NODES) {
        float cv = C[(long)row * 64 + oc];
        float I = frcp(1.f + __expf(-(acc[j][r] + bI + wcI * cv)));
        float F = frcp(1.f + __expf(-(acc[4 + j][r] + bF + wcF * cv)));
        float e2 = __expf(2.f * (acc[8 + j][r] + bT));
        float T = 1.f - 2.f * frcp(e2 + 1.f);
        float cn = F * cv + I * T;
        float O = frcp(1.f + __expf(-(acc[12 + j][r] + bO + wcO * cn)));
        float e2c = __expf(2.f * cn);
        float tc = 1.f - 2.f * frcp(e2c + 1.f);
        Hout[(long)row * 64 + oc] = O * tc;
        Cout[(long)row * 64 + oc] = cn;
      }
    }
  }
}

extern "C" void kernel_launch(void* const* d_in, const int* in_sizes, int n_in,
                              void* d_out, int out_size, void* d_ws, size_t ws_size,
                              hipStream_t stream) {
  (void)in_sizes; (void)n_in; (void)out_size; (void)ws_size;
  const float* X   = (const float*)d_in[0];
  const int*   ei  = (const int*)d_in[1];
  const float* ew  = (const float*)d_in[2];
  const float* H   = (const float*)d_in[3];
  const float* C   = (const float*)d_in[4];
  const float* Wxi = (const float*)d_in[5];
  const float* bxi = (const float*)d_in[6];
  const float* Wxf = (const float*)d_in[7];
  const float* bxf = (const float*)d_in[8];
  const float* Wxc = (const float*)d_in[9];
  const float* bxc = (const float*)d_in[10];
  const float* Wxo = (const float*)d_in[11];
  const float* bxo = (const float*)d_in[12];
  const float* Whi = (const float*)d_in[13];
  const float* bhi = (const float*)d_in[14];
  const float* Whf = (const float*)d_in[15];
  const float* bhf = (const float*)d_in[16];
  const float* Whc = (const float*)d_in[17];
  const float* bhc = (const float*)d_in[18];
  const float* Who = (const float*)d_in[19];
  const float* bho = (const float*)d_in[20];
  const float* wci = (const float*)d_in[21];
  const float* wcf = (const float*)d_in[22];
  const float* wco = (const float*)d_in[23];
  const float* bi  = (const float*)d_in[24];
  const float* bf_ = (const float*)d_in[25];
  const float* bc_ = (const float*)d_in[26];
  const float* bo  = (const float*)d_in[27];

  float* ws = (float*)d_ws;
  uint*   blkh  = (uint*)(ws + O_BLKH);
  uint*   bbase = (uint*)(ws + O_BBASE);
  int*    cnt   = (int*)(ws + O_CNT);
  float*  dinv  = ws + O_DINV;
  int*    rptr  = (int*)(ws + O_RPTR);
  unsigned long long* srec  = (unsigned long long*)(ws + O_SREC);
  unsigned long long* srec2 = (unsigned long long*)(ws + O_SREC2);
  uint*   edges = (uint*)(ws + O_EDGE);
  uint*   XHb   = (uint*)(ws + O_XHB);
  uint*   T1b   = (uint*)(ws + O_T1B);
  uint*   T2b   = (uint*)(ws + O_T2B);
  ushort* Bp    = (ushort*)(ws + O_BP);

  float* Hout = (float*)d_out;
  float* Cout = Hout + N_NODES * 64;

  k_hist<<<PBLK, 256, 0, stream>>>(ei, blkh);
  k_scan_g<<<1, 1024, 0, stream>>>(blkh, bbase);
  k_scatter_b<<<PBLK, 256, 0, stream>>>(ei, ew, blkh, srec);
  k_csr<<<NBKT, 256, 0, stream>>>(srec, bbase, srec2, cnt, dinv, rptr);
  k_finalize<<<NBKT, 256, 0, stream>>>(srec2, bbase, dinv, edges);
  k_xhb<<<(N_NODES * 64 + 255) / 256, 256, 0, stream>>>(X, H, XHb);
  k_pack<<<(12 * 16 * 64 * 8 + 255) / 256, 256, 0, stream>>>(Wxi, Wxf, Wxc, Wxo,
                                                             Whi, Whf, Whc, Who, Bp);
  int spmm_grid = (N_NODES + 3) / 4;
  // T1 = L @ XH
  k_spmm2b<<<spmm_grid, 256, 0, stream>>>(XHb, XHb, 1.f, 0.f, rptr, cnt, edges, T1b);
  // T2 = 2 L @ T1 - XH
  k_spmm2b<<<spmm_grid, 256, 0, stream>>>(T1b, XHb, 2.f, -1.f, rptr, cnt, edges, T2b);
  k_mfma_lstm<<<(N_NODES + 63) / 64, 256, 0, stream>>>(
      (const ushort*)XHb, (const ushort*)T1b, (const ushort*)T2b, C, Bp,
      bxi, bxf, bxc, bxo, bhi, bhf, bhc, bho,
      wci, wcf, wco, bi, bf_, bc_, bo, Hout, Cout);
}

// Round 8
// 223.877 us; speedup vs baseline: 4.6390x; 1.2899x over previous
//
#include <hip/hip_runtime.h>
#include <hip/hip_bf16.h>
#include <math.h>

#define N_NODES 50000
#define E_EDGES 1600000
#define NBKT 196          // row buckets of 256 rows
#define PBLK 400          // blocks in hist/scatter phases
#define CHUNK 4000        // edges per block (PBLK*CHUNK == E_EDGES)

typedef __attribute__((ext_vector_type(8))) short s8v;    // 8 bf16 frag
typedef __attribute__((ext_vector_type(4))) float f32x4;  // mfma acc

// ---------------- workspace layout (float units) ----------------
#define O_BLKH  0          // 196*400 u32, local-scanned in place
#define O_BBASE 78592      // 197 u32 bucket bases
#define O_BSUM  78848      // 196 u32 bucket totals
#define O_CNT   79104      // 50000 i32
#define O_DINV  129152     // 50000 f32
#define O_RPTR  179200     // 50000 i32
#define O_SREC  229248     // 1.6M u64 records = 3.2M floats
#define O_SREC2 3429248    // 1.6M u64 sorted records
#define O_EDGE  O_SREC     // alias: final u32 edges (srec dead after k_csr)
#define O_XHB   O_SREC2    // alias: XHb written after k_finalize (srec2 dead)
#define O_T1B   6629248
#define O_T2B   9829248
#define O_BP    13029248   // 98304 bf16
// end: 13078400 floats ~= 52.3 MB

__device__ __forceinline__ uint pk_bf16(float x, float y) {
  __hip_bfloat16 bx = __float2bfloat16(x), by = __float2bfloat16(y);
  ushort ux = *reinterpret_cast<ushort*>(&bx);
  ushort uy = *reinterpret_cast<ushort*>(&by);
  return ((uint)uy << 16) | (uint)ux;
}

// ---- phase 1: per-block bucket histogram (no global atomics) ----
__global__ __launch_bounds__(256) void k_hist(const int* __restrict__ ei,
                                              uint* __restrict__ blkh) {
  __shared__ uint h[NBKT];
  int blk = blockIdx.x, tid = threadIdx.x;
  for (int i = tid; i < NBKT; i += 256) h[i] = 0;
  __syncthreads();
  int e0 = blk * CHUNK;
  for (int i = tid; i < CHUNK; i += 256) {
    int e = e0 + i;
    int r = ei[e], c = ei[E_EDGES + e];
    if (r != c) atomicAdd(&h[r >> 8], 1u);
  }
  __syncthreads();
  for (int i = tid; i < NBKT; i += 256) blkh[i * PBLK + blk] = h[i];  // [bucket][block]
}

// ---- phase 2a: per-bucket exclusive scan of its 400 block counts (in place)
//      + bucket total. 196 parallel blocks, LDS Hillis-Steele over 512 slots.
__global__ __launch_bounds__(256) void k_bsum_scan(uint* __restrict__ blkh,
                                                   uint* __restrict__ bsum) {
  __shared__ uint sh[512];
  int b = blockIdx.x, t = threadIdx.x;
  uint v0 = (t < PBLK) ? blkh[b * PBLK + t] : 0u;
  uint v1 = (t + 256 < PBLK) ? blkh[b * PBLK + t + 256] : 0u;
  sh[t] = v0; sh[t + 256] = v1;
  __syncthreads();
  for (int off = 1; off < 512; off <<= 1) {
    uint x0 = sh[t], x1 = sh[t + 256];
    uint a0 = (t >= off) ? sh[t - off] : 0u;
    uint a1 = (t + 256 >= off) ? sh[t + 256 - off] : 0u;
    __syncthreads();
    sh[t] = x0 + a0; sh[t + 256] = x1 + a1;
    __syncthreads();
  }
  if (t < PBLK) blkh[b * PBLK + t] = sh[t] - v0;          // local exclusive
  if (t + 256 < PBLK) blkh[b * PBLK + t + 256] = sh[t + 256] - v1;
  if (t == 0) bsum[b] = sh[511];
}

// ---- phase 2b: scan 196 bucket totals -> bbase[0..196] (single tiny block) ----
__global__ __launch_bounds__(256) void k_bscan(const uint* __restrict__ bsum,
                                               uint* __restrict__ bbase) {
  __shared__ uint sh[256];
  int t = threadIdx.x;
  uint v = (t < NBKT) ? bsum[t] : 0u;
  sh[t] = v;
  __syncthreads();
  for (int off = 1; off < 256; off <<= 1) {
    uint a = (t >= off) ? sh[t - off] : 0u;
    __syncthreads();
    sh[t] += a;
    __syncthreads();
  }
  if (t < NBKT) bbase[t] = sh[t] - v;
  if (t == 255) bbase[NBKT] = sh[255];
}

// ---- phase 3: scatter edges to bucket-contiguous u64 records via LDS cursors ----
__global__ __launch_bounds__(256) void k_scatter_b(const int* __restrict__ ei,
                                                   const float* __restrict__ ew,
                                                   const uint* __restrict__ off,
                                                   const uint* __restrict__ bbase,
                                                   unsigned long long* __restrict__ srec) {
  __shared__ uint cur[NBKT];
  int blk = blockIdx.x, tid = threadIdx.x;
  for (int i = tid; i < NBKT; i += 256) cur[i] = off[i * PBLK + blk] + bbase[i];
  __syncthreads();
  int e0 = blk * CHUNK;
  for (int i = tid; i < CHUNK; i += 256) {
    int e = e0 + i;
    int r = ei[e], c = ei[E_EDGES + e];
    if (r != c) {
      uint pos = atomicAdd(&cur[r >> 8], 1u);
      srec[pos] = ((unsigned long long)(r & 255) << 48) |
                  ((unsigned long long)(uint)c << 32) |
                  (unsigned long long)__float_as_uint(ew[e]);
    }
  }
}

// ---- phase 4: per-bucket CSR build + degree/dinv (LDS atomics only) ----
__global__ __launch_bounds__(256) void k_csr(const unsigned long long* __restrict__ srec,
                                             const uint* __restrict__ bbase,
                                             unsigned long long* __restrict__ srec2,
                                             int* __restrict__ cnt, float* __restrict__ dinv,
                                             int* __restrict__ rptr) {
  __shared__ uint hc[256], hs[256], cur[256], wsum[4];
  int b = blockIdx.x, t = threadIdx.x;
  uint start = bbase[b], endv = bbase[b + 1];
  hc[t] = 0; hs[t] = 0;
  __syncthreads();
  for (uint i = start + t; i < endv; i += 256) {
    unsigned long long rec = srec[i];
    int rl = (int)(rec >> 48);
    float w = __uint_as_float((uint)rec);
    atomicAdd(&hc[rl], 1u);
    atomicAdd(&hs[rl], (uint)(w * 1048576.0f + 0.5f));  // fixed 2^20
  }
  __syncthreads();
  int lane = t & 63, wid = t >> 6;
  uint myc = hc[t];
  uint x = myc;
#pragma unroll
  for (int off = 1; off < 64; off <<= 1) {
    uint y = __shfl_up(x, off);
    if (lane >= off) x += y;
  }
  if (lane == 63) wsum[wid] = x;
  __syncthreads();
  uint woff = 0;
#pragma unroll
  for (int j = 0; j < 4; ++j) if (j < wid) woff += wsum[j];
  uint excl = woff + x - myc;
  int row = b * 256 + t;
  if (row < N_NODES) {
    float d = (float)hs[t] * (1.0f / 1048576.0f);
    dinv[row] = d > 0.f ? rsqrtf(d) : 0.f;
    cnt[row] = (int)myc;
    rptr[row] = (int)(start + excl);
  }
  cur[t] = start + excl;
  __syncthreads();
  for (uint i = start + t; i < endv; i += 256) {
    unsigned long long rec = srec[i];
    int rl = (int)(rec >> 48);
    uint pos = atomicAdd(&cur[rl], 1u);
    srec2[pos] = rec;
  }
}

// ---- phase 5: fold dinv into weights, emit final u32 edge records ----
__global__ __launch_bounds__(256) void k_finalize(const unsigned long long* __restrict__ srec2,
                                                  const uint* __restrict__ bbase,
                                                  const float* __restrict__ dinv,
                                                  uint* __restrict__ edges) {
  int b = blockIdx.x, t = threadIdx.x;
  uint start = bbase[b], endv = bbase[b + 1];
  for (uint i = start + t; i < endv; i += 256) {
    unsigned long long rec = srec2[i];
    int rl = (int)(rec >> 48);
    int c = (int)((rec >> 32) & 0xffff);
    float w = __uint_as_float((uint)rec);
    int r = b * 256 + rl;
    float wn = -w * dinv[r] * dinv[c];
    __hip_bfloat16 bw = __float2bfloat16(wn);
    edges[i] = ((uint)c << 16) | (uint)*reinterpret_cast<ushort*>(&bw);
  }
}

// XHb[n] = bf16x2-packed [X[n] | H[n]]  (u32 = 2 channels per thread)
__global__ void k_xhb(const float* __restrict__ X, const float* __restrict__ Hm,
                      uint* __restrict__ XHb) {
  int t = blockIdx.x * blockDim.x + threadIdx.x;
  if (t >= N_NODES * 64) return;
  int n = t >> 6, q = t & 63;
  float2 v = (q < 32) ? *(const float2*)(X + (long)n * 64 + q * 2)
                      : *(const float2*)(Hm + (long)n * 64 + (q - 32) * 2);
  XHb[t] = pk_bf16(v.x, v.y);
}

// out[row] = alpha*(L@src)[row] + beta*other[row]; wave/row, lane = 2 bf16 channels
__global__ __launch_bounds__(256) void k_spmm2b(
    const uint* __restrict__ src, const uint* __restrict__ other,
    float alpha, float beta,
    const int* __restrict__ rptr, const int* __restrict__ cnt,
    const uint* __restrict__ edges, uint* __restrict__ out) {
  int wid = threadIdx.x >> 6, lane = threadIdx.x & 63;
  int row = blockIdx.x * 4 + wid;
  if (row >= N_NODES) return;
  int start = rptr[row], n = cnt[row];
  float ax = 0.f, ay = 0.f;
  for (int base = 0; base < n; base += 64) {
    int rem = n - base;
    int m = rem < 64 ? rem : 64;
    uint rec = (lane < m) ? edges[start + base + lane] : 0u;
    int j = 0;
    for (; j + 4 <= m; j += 4) {
#pragma unroll
      for (int u = 0; u < 4; ++u) {
        uint r = __shfl(rec, j + u);
        int cc = (int)(r >> 16);
        float ww = __uint_as_float(r << 16);
        uint z = src[cc * 64 + lane];
        ax = fmaf(ww, __uint_as_float(z << 16), ax);
        ay = fmaf(ww, __uint_as_float(z & 0xffff0000u), ay);
      }
    }
    for (; j < m; ++j) {
      uint r = __shfl(rec, j);
      int cc = (int)(r >> 16);
      float ww = __uint_as_float(r << 16);
      uint z = src[cc * 64 + lane];
      ax = fmaf(ww, __uint_as_float(z << 16), ax);
      ay = fmaf(ww, __uint_as_float(z & 0xffff0000u), ay);
    }
  }
  float ox = alpha * ax, oy = alpha * ay;
  if (beta != 0.f) {
    uint ov = other[row * 64 + lane];
    ox += beta * __uint_as_float(ov << 16);
    oy += beta * __uint_as_float(ov & 0xffff0000u);
  }
  out[row * 64 + lane] = pk_bf16(ox, oy);
}

// B-frag pack: Bp[((t*16+c)*64+lane)*8+j] = bf16(W[k][col]), k=t*32+(lane>>4)*8+j,
// col = c*16+(lane&15); col = g*64+oc; k-slice s=k/64: even->Wx[g], odd->Wh[g], ord=s>>1
__global__ void k_pack(const float* __restrict__ Wxi, const float* __restrict__ Wxf,
                       const float* __restrict__ Wxc, const float* __restrict__ Wxo,
                       const float* __restrict__ Whi, const float* __restrict__ Whf,
                       const float* __restrict__ Whc, const float* __restrict__ Who,
                       ushort* __restrict__ Bp) {
  int idx = blockIdx.x * blockDim.x + threadIdx.x;
  if (idx >= 12 * 16 * 64 * 8) return;
  int j = idx & 7;
  int lane = (idx >> 3) & 63;
  int c = (idx >> 9) & 15;
  int t = idx >> 13;
  int k = t * 32 + (lane >> 4) * 8 + j;
  int col = c * 16 + (lane & 15);
  int g = col >> 6, oc = col & 63;
  int s = k >> 6, kk = k & 63, ord = s >> 1;
  const float* Wx[4] = {Wxi, Wxf, Wxc, Wxo};
  const float* Wh[4] = {Whi, Whf, Whc, Who};
  const float* W = (s & 1) ? Wh[g] : Wx[g];
  float v = W[(ord * 64 + kk) * 64 + oc];
  __hip_bfloat16 b = __float2bfloat16(v);
  Bp[idx] = *reinterpret_cast<ushort*>(&b);
}

__device__ __forceinline__ float frcp(float x) { return __builtin_amdgcn_rcpf(x); }

// MFMA GEMM: [XHb|T1b|T2b][N,384] @ W[384,256] + fused LSTM epilogue.
// Block = 4 waves x 16 rows = 64 rows; wave computes 16x256 via 16 16x16x32 tiles.
// A: all 12 frags prefetched. B: LDS double-buffered via global_load_lds.
__global__ __launch_bounds__(256) void k_mfma_lstm(
    const ushort* __restrict__ XHb, const ushort* __restrict__ T1b,
    const ushort* __restrict__ T2b, const float* __restrict__ C,
    const ushort* __restrict__ Bp,
    const float* __restrict__ bxi, const float* __restrict__ bxf,
    const float* __restrict__ bxc, const float* __restrict__ bxo,
    const float* __restrict__ bhi, const float* __restrict__ bhf,
    const float* __restrict__ bhc, const float* __restrict__ bho,
    const float* __restrict__ wci, const float* __restrict__ wcf, const float* __restrict__ wco,
    const float* __restrict__ bi, const float* __restrict__ bf_,
    const float* __restrict__ bc_, const float* __restrict__ bo,
    float* __restrict__ Hout, float* __restrict__ Cout) {
  __shared__ ushort bsh[2][8192];  // 2 x 16 KB B tiles
  int lane = threadIdx.x & 63, wid = threadIdx.x >> 6;
  int row0 = blockIdx.x * 64 + wid * 16;
  int ar = row0 + (lane & 15);
  if (ar > N_NODES - 1) ar = N_NODES - 1;  // clamp: dup rows, outputs masked later
  long abase = (long)ar * 128 + (lane >> 4) * 8;

#define STAGE(buf, t)                                                          \
  {                                                                            \
    _Pragma("unroll") for (int q = 0; q < 4; ++q) {                            \
      int seg = wid * 4 + q;                                                   \
      __builtin_amdgcn_global_load_lds(                                        \
          (const __attribute__((address_space(1))) uint*)(Bp + (t)*8192 +     \
                                                          seg * 512 + lane * 8),\
          (__attribute__((address_space(3))) uint*)&bsh[buf][seg * 512],       \
          16, 0, 0);                                                           \
    }                                                                          \
  }

  STAGE(0, 0)

  s8v a[12];
#pragma unroll
  for (int q = 0; q < 4; ++q) a[q] = *(const s8v*)(XHb + abase + q * 32);
#pragma unroll
  for (int q = 0; q < 4; ++q) a[4 + q] = *(const s8v*)(T1b + abase + q * 32);
#pragma unroll
  for (int q = 0; q < 4; ++q) a[8 + q] = *(const s8v*)(T2b + abase + q * 32);

  f32x4 acc[16];
#pragma unroll
  for (int c = 0; c < 16; ++c) acc[c] = {0.f, 0.f, 0.f, 0.f};

#pragma unroll
  for (int t = 0; t < 12; ++t) {
    int buf = t & 1;
    __syncthreads();
    if (t < 11) STAGE(buf ^ 1, t + 1)
    const ushort* bp = &bsh[buf][lane * 8];
#pragma unroll
    for (int c = 0; c < 16; ++c) {
      s8v b = *(const s8v*)(bp + c * 512);
      acc[c] = __builtin_amdgcn_mfma_f32_16x16x32_bf16(a[t], b, acc[c], 0, 0, 0);
    }
  }
#undef STAGE

  int rbase = row0 + ((lane >> 4) << 2);
  int ocl = lane & 15;
#pragma unroll
  for (int j = 0; j < 4; ++j) {
    int oc = j * 16 + ocl;
    float bI = bxi[oc] + bhi[oc] + bi[oc];
    float bF = bxf[oc] + bhf[oc] + bf_[oc];
    float bT = bxc[oc] + bhc[oc] + bc_[oc];
    float bO = bxo[oc] + bho[oc] + bo[oc];
    float wcI = wci[oc], wcF = wcf[oc], wcO = wco[oc];
#pragma unroll
    for (int r = 0; r < 4; ++r) {
      int row = rbase + r;
      if (row < N_NODES) {
        float cv = C[(long)row * 64 + oc];
        float I = frcp(1.f + __expf(-(acc[j][r] + bI + wcI * cv)));
        float F = frcp(1.f + __expf(-(acc[4 + j][r] + bF + wcF * cv)));
        float e2 = __expf(2.f * (acc[8 + j][r] + bT));
        float T = 1.f - 2.f * frcp(e2 + 1.f);
        float cn = F * cv + I * T;
        float O = frcp(1.f + __expf(-(acc[12 + j][r] + bO + wcO * cn)));
        float e2c = __expf(2.f * cn);
        float tc = 1.f - 2.f * frcp(e2c + 1.f);
        Hout[(long)row * 64 + oc] = O * tc;
        Cout[(long)row * 64 + oc] = cn;
      }
    }
  }
}

extern "C" void kernel_launch(void* const* d_in, const int* in_sizes, int n_in,
                              void* d_out, int out_size, void* d_ws, size_t ws_size,
                              hipStream_t stream) {
  (void)in_sizes; (void)n_in; (void)out_size; (void)ws_size;
  const float* X   = (const float*)d_in[0];
  const int*   ei  = (const int*)d_in[1];
  const float* ew  = (const float*)d_in[2];
  const float* H   = (const float*)d_in[3];
  const float* C   = (const float*)d_in[4];
  const float* Wxi = (const float*)d_in[5];
  const float* bxi = (const float*)d_in[6];
  const float* Wxf = (const float*)d_in[7];
  const float* bxf = (const float*)d_in[8];
  const float* Wxc = (const float*)d_in[9];
  const float* bxc = (const float*)d_in[10];
  const float* Wxo = (const float*)d_in[11];
  const float* bxo = (const float*)d_in[12];
  const float* Whi = (const float*)d_in[13];
  const float* bhi = (const float*)d_in[14];
  const float* Whf = (const float*)d_in[15];
  const float* bhf = (const float*)d_in[16];
  const float* Whc = (const float*)d_in[17];
  const float* bhc = (const float*)d_in[18];
  const float* Who = (const float*)d_in[19];
  const float* bho = (const float*)d_in[20];
  const float* wci = (const float*)d_in[21];
  const float* wcf = (const float*)d_in[22];
  const float* wco = (const float*)d_in[23];
  const float* bi  = (const float*)d_in[24];
  const float* bf_ = (const float*)d_in[25];
  const float* bc_ = (const float*)d_in[26];
  const float* bo  = (const float*)d_in[27];

  float* ws = (float*)d_ws;
  uint*   blkh  = (uint*)(ws + O_BLKH);
  uint*   bbase = (uint*)(ws + O_BBASE);
  uint*   bsum  = (uint*)(ws + O_BSUM);
  int*    cnt   = (int*)(ws + O_CNT);
  float*  dinv  = ws + O_DINV;
  int*    rptr  = (int*)(ws + O_RPTR);
  unsigned long long* srec  = (unsigned long long*)(ws + O_SREC);
  unsigned long long* srec2 = (unsigned long long*)(ws + O_SREC2);
  uint*   edges = (uint*)(ws + O_EDGE);
  uint*   XHb   = (uint*)(ws + O_XHB);
  uint*   T1b   = (uint*)(ws + O_T1B);
  uint*   T2b   = (uint*)(ws + O_T2B);
  ushort* Bp    = (ushort*)(ws + O_BP);

  float* Hout = (float*)d_out;
  float* Cout = Hout + N_NODES * 64;

  k_hist<<<PBLK, 256, 0, stream>>>(ei, blkh);
  k_bsum_scan<<<NBKT, 256, 0, stream>>>(blkh, bsum);
  k_bscan<<<1, 256, 0, stream>>>(bsum, bbase);
  k_scatter_b<<<PBLK, 256, 0, stream>>>(ei, ew, blkh, bbase, srec);
  k_csr<<<NBKT, 256, 0, stream>>>(srec, bbase, srec2, cnt, dinv, rptr);
  k_finalize<<<NBKT, 256, 0, stream>>>(srec2, bbase, dinv, edges);
  k_xhb<<<(N_NODES * 64 + 255) / 256, 256, 0, stream>>>(X, H, XHb);
  k_pack<<<(12 * 16 * 64 * 8 + 255) / 256, 256, 0, stream>>>(Wxi, Wxf, Wxc, Wxo,
                                                             Whi, Whf, Whc, Who, Bp);
  int spmm_grid = (N_NODES + 3) / 4;
  // T1 = L @ XH
  k_spmm2b<<<spmm_grid, 256, 0, stream>>>(XHb, XHb, 1.f, 0.f, rptr, cnt, edges, T1b);
  // T2 = 2 L @ T1 - XH
  k_spmm2b<<<spmm_grid, 256, 0, stream>>>(T1b, XHb, 2.f, -1.f, rptr, cnt, edges, T2b);
  k_mfma_lstm<<<(N_NODES + 63) / 64, 256, 0, stream>>>(
      (const ushort*)XHb, (const ushort*)T1b, (const ushort*)T2b, C, Bp,
      bxi, bxf, bxc, bxo, bhi, bhf, bhc, bho,
      wci, wcf, wco, bi, bf_, bc_, bo, Hout, Cout);
}